// Round 14
// baseline (316.830 us; speedup 1.0000x reference)
//
#include <hip/hip_runtime.h>
#include <hip/hip_fp16.h>

#define D 128
#define NDRUG 20000
#define NDIS 20000
#define EDGES 640000
#define LROWS 200000
#define ROWP 264   // LDS row pitch in halves: 256 data + 8 pad (528B, 16B-aligned)

typedef unsigned short u16;
typedef __attribute__((ext_vector_type(8))) _Float16 h8v;
typedef __attribute__((ext_vector_type(4))) float f4v;

// ---------------- helpers ----------------

__device__ inline void h8_load(uint4 u, float f[8]) {
    float2 a = __half22float2(*(const __half2*)&u.x);
    float2 b = __half22float2(*(const __half2*)&u.y);
    float2 c = __half22float2(*(const __half2*)&u.z);
    float2 d = __half22float2(*(const __half2*)&u.w);
    f[0] = a.x; f[1] = a.y; f[2] = b.x; f[3] = b.y;
    f[4] = c.x; f[5] = c.y; f[6] = d.x; f[7] = d.y;
}

// ---------------- CSR build: slice-local atomics, no rank array ----------------
// Slice s = blockIdx%8 -> consecutive blocks round-robin across XCDs, so the
// 10KB counter slice (and csr slice) lives in ONE XCD's L2: atomics never
// bounce across XCDs. Cost: dst[] re-read x8 (~41MB total, ~7us of BW).

#define HS 13    // hist subchunks per slice per direction
#define SB 104   // scatter subchunks per slice per direction

__global__ __launch_bounds__(256) void hist_sliced_kernel(
    const int* __restrict__ dstA, int* __restrict__ cntA,
    const int* __restrict__ dstB, int* __restrict__ cntB, int n)
{
    int b = blockIdx.x;
    int dirB = (b >= 8 * HS);
    int bb = b - (dirB ? 8 * HS : 0);
    int s = bb & 7;
    int sub = bb >> 3;
    const int* dst = dirB ? dstB : dstA;
    int* cnt = dirB ? cntB : cntA;

    const int lo = s * 2500, hi = lo + 2500;
    const int chunk = (n + HS - 1) / HS;
    int i0 = sub * chunk;
    int i1 = i0 + chunk; i1 = i1 < n ? i1 : n;
    for (int i = i0 + threadIdx.x; i < i1; i += 256) {
        int d = dst[i];
        if (d >= lo && d < hi) atomicAdd(&cnt[d], 1);
    }
}

__global__ __launch_bounds__(1024) void scan2_kernel(int* __restrict__ c0, int* __restrict__ o0,
                                                     int* __restrict__ c1, int* __restrict__ o1,
                                                     int n) {
    int* cnt_io = (blockIdx.x == 0) ? c0 : c1;
    int* off    = (blockIdx.x == 0) ? o0 : o1;
    __shared__ int wsum[16];
    __shared__ int carry_s;
    const int tid = threadIdx.x;
    const int lane = tid & 63;
    const int wid = tid >> 6;
    if (tid == 0) { carry_s = 0; off[0] = 0; }
    __syncthreads();
    for (int start = 0; start < n; start += 1024) {
        int i = start + tid;
        int v = (i < n) ? cnt_io[i] : 0;
        int carry = carry_s;
        int s = v;
        #pragma unroll
        for (int o = 1; o < 64; o <<= 1) {
            int t = __shfl_up(s, o, 64);
            if (lane >= o) s += t;
        }
        if (lane == 63) wsum[wid] = s;
        __syncthreads();
        if (wid == 0) {
            int ws = (lane < 16) ? wsum[lane] : 0;
            #pragma unroll
            for (int o = 1; o < 16; o <<= 1) {
                int t = __shfl_up(ws, o, 64);
                if (lane >= o) ws += t;
            }
            if (lane < 16) wsum[lane] = ws;
        }
        __syncthreads();
        int woff = (wid > 0) ? wsum[wid - 1] : 0;
        int incl = s + woff + carry;
        if (i < n) {
            off[i + 1] = incl;
            cnt_io[i] = incl - v;   // exclusive start -> scatter cursor
        }
        __syncthreads();
        if (tid == 1023) carry_s = incl;
        __syncthreads();
    }
}

__global__ __launch_bounds__(256) void scatter_atomic_kernel(
    const int* __restrict__ srcA, const int* __restrict__ dstA,
    int* __restrict__ curA, u16* __restrict__ csrA,
    const int* __restrict__ srcB, const int* __restrict__ dstB,
    int* __restrict__ curB, u16* __restrict__ csrB, int n)
{
    int b = blockIdx.x;
    int dirB = (b >= 8 * SB);
    int bb = b - (dirB ? 8 * SB : 0);
    int s = bb & 7;
    int sub = bb >> 3;
    const int* src = dirB ? srcB : srcA;
    const int* dst = dirB ? dstB : dstA;
    int* cur = dirB ? curB : curA;
    u16* csr = dirB ? csrB : csrA;

    const int lo = s * 2500, hi = lo + 2500;
    const int chunk = (n + SB - 1) / SB;
    int i0 = sub * chunk;
    int i1 = i0 + chunk; i1 = i1 < n ? i1 : n;
    for (int i = i0 + threadIdx.x; i < i1; i += 256) {
        int d = dst[i];
        if (d >= lo && d < hi) {
            int pos = atomicAdd(&cur[d], 1);
            csr[pos] = (u16)src[i];
        }
    }
}

// ---------------- fp32 -> fp16 conversions ----------------

// both feature tables in one dispatch
__global__ __launch_bounds__(256) void cvt16x2_kernel(
    const float* __restrict__ ina, __half* __restrict__ outa, int n4a,
    const float* __restrict__ inb, __half* __restrict__ outb, int n4b)
{
    int i = blockIdx.x * blockDim.x + threadIdx.x;
    const float* in; __half* out; int idx;
    if (i < n4a) { in = ina; out = outa; idx = i; }
    else if (i - n4a < n4b) { in = inb; out = outb; idx = i - n4a; }
    else return;
    float4 v = ((const float4*)in)[idx];
    __half2 a = __floats2half2_rn(v.x, v.y);
    __half2 b = __floats2half2_rn(v.z, v.w);
    uint2 u;
    u.x = *(unsigned*)&a;
    u.y = *(unsigned*)&b;
    ((uint2*)out)[idx] = u;
}

// Transposed, stacked fp16 weights for MFMA B-operands (r13-proven).
__global__ __launch_bounds__(256) void cvtwt_kernel(
    const float* __restrict__ W1l_d2s, const float* __restrict__ W1r_d2s,
    const float* __restrict__ W1l_s2d, const float* __restrict__ W1r_s2d,
    const float* __restrict__ W2l_d2s, const float* __restrict__ W2r_d2s,
    const float* __restrict__ W2l_s2d, const float* __restrict__ W2r_s2d,
    const float* __restrict__ decW1, __half* __restrict__ out)
{
    int gid = blockIdx.x * 256 + threadIdx.x;
    float v;
    if (gid < 4 * 32768) {
        int chunk = gid >> 15;
        int r = gid & 32767;
        int col = r >> 8;
        int k = r & 255;
        const float *Wl, *Wr;
        switch (chunk) {
            case 0: Wl = W1l_d2s; Wr = W1r_d2s; break;
            case 1: Wl = W1l_s2d; Wr = W1r_s2d; break;
            case 2: Wl = W2l_d2s; Wr = W2r_d2s; break;
            default: Wl = W2l_s2d; Wr = W2r_s2d; break;
        }
        const float* src = (k < 128) ? Wl : Wr;
        v = src[(size_t)(k & 127) * D + col];
    } else {
        int r = gid - 4 * 32768;
        int chunk = r >> 14;            // 0 = hi (rows 128-255), 1 = lo
        int q = r & 16383;
        int col = q >> 7;
        int k = q & 127;
        int row = k + (chunk == 0 ? 128 : 0);
        v = decW1[(size_t)row * D + col];
    }
    out[gid] = __float2half_rn(v);
}

// ---------------- SAGE gather (r8-proven inner loop; fp16 LDS tail) ----------------
// DO NOT restructure the readlane/half-wave loop — r5/r7 variants blew up
// to 200 VGPR / 11% occupancy.

__device__ inline void sage_gather(
    const __half* __restrict__ xsrc, const __half* __restrict__ xdst,
    const int* __restrict__ off, const u16* __restrict__ csr,
    __half sm[16][ROWP], int node0, int row0, int lane)
{
    const bool hiHalf = lane >= 32;
    const int lq = lane & 31;
    const int c0 = lq * 4;          // 4 halves (8B) per lane
    for (int r = 0; r < 4; ++r) {
        int node = node0 + r;
        int e0 = off[node], e1 = off[node + 1];
        int deg = e1 - e0;
        float a0 = 0.f, a1 = 0.f, a2 = 0.f, a3 = 0.f;
        for (int base = e0; base < e1; base += 64) {
            int nv = e1 - base; nv = nv < 64 ? nv : 64;
            int myidx = 0;
            if (lane < nv) myidx = csr[base + lane];
            int npair = nv >> 1;
            int t = 0;
            for (; t + 4 <= npair; t += 4) {
                int pa0 = __builtin_amdgcn_readlane(myidx, 2 * t + 0);
                int pb0 = __builtin_amdgcn_readlane(myidx, 2 * t + 1);
                int pa1 = __builtin_amdgcn_readlane(myidx, 2 * t + 2);
                int pb1 = __builtin_amdgcn_readlane(myidx, 2 * t + 3);
                int pa2 = __builtin_amdgcn_readlane(myidx, 2 * t + 4);
                int pb2 = __builtin_amdgcn_readlane(myidx, 2 * t + 5);
                int pa3 = __builtin_amdgcn_readlane(myidx, 2 * t + 6);
                int pb3 = __builtin_amdgcn_readlane(myidx, 2 * t + 7);
                int s0 = hiHalf ? pb0 : pa0;
                int s1 = hiHalf ? pb1 : pa1;
                int s2 = hiHalf ? pb2 : pa2;
                int s3 = hiHalf ? pb3 : pa3;
                uint2 u0 = *(const uint2*)(xsrc + (size_t)s0 * D + c0);
                uint2 u1 = *(const uint2*)(xsrc + (size_t)s1 * D + c0);
                uint2 u2 = *(const uint2*)(xsrc + (size_t)s2 * D + c0);
                uint2 u3 = *(const uint2*)(xsrc + (size_t)s3 * D + c0);
                float2 t0, t1;
                t0 = __half22float2(*(const __half2*)&u0.x);
                t1 = __half22float2(*(const __half2*)&u0.y);
                a0 += t0.x; a1 += t0.y; a2 += t1.x; a3 += t1.y;
                t0 = __half22float2(*(const __half2*)&u1.x);
                t1 = __half22float2(*(const __half2*)&u1.y);
                a0 += t0.x; a1 += t0.y; a2 += t1.x; a3 += t1.y;
                t0 = __half22float2(*(const __half2*)&u2.x);
                t1 = __half22float2(*(const __half2*)&u2.y);
                a0 += t0.x; a1 += t0.y; a2 += t1.x; a3 += t1.y;
                t0 = __half22float2(*(const __half2*)&u3.x);
                t1 = __half22float2(*(const __half2*)&u3.y);
                a0 += t0.x; a1 += t0.y; a2 += t1.x; a3 += t1.y;
            }
            for (; t < npair; ++t) {
                int pa = __builtin_amdgcn_readlane(myidx, 2 * t + 0);
                int pb = __builtin_amdgcn_readlane(myidx, 2 * t + 1);
                int s = hiHalf ? pb : pa;
                uint2 u = *(const uint2*)(xsrc + (size_t)s * D + c0);
                float2 t0 = __half22float2(*(const __half2*)&u.x);
                float2 t1 = __half22float2(*(const __half2*)&u.y);
                a0 += t0.x; a1 += t0.y; a2 += t1.x; a3 += t1.y;
            }
            if (nv & 1) {
                int s = __builtin_amdgcn_readlane(myidx, nv - 1);
                if (!hiHalf) {
                    uint2 u = *(const uint2*)(xsrc + (size_t)s * D + c0);
                    float2 t0 = __half22float2(*(const __half2*)&u.x);
                    float2 t1 = __half22float2(*(const __half2*)&u.y);
                    a0 += t0.x; a1 += t0.y; a2 += t1.x; a3 += t1.y;
                }
            }
        }
        a0 += __shfl_xor(a0, 32, 64);
        a1 += __shfl_xor(a1, 32, 64);
        a2 += __shfl_xor(a2, 32, 64);
        a3 += __shfl_xor(a3, 32, 64);
        float inv = 1.0f / (float)(deg < 1 ? 1 : deg);
        if (!hiHalf) {
            __half2 h01 = __floats2half2_rn(a0 * inv, a1 * inv);
            __half2 h23 = __floats2half2_rn(a2 * inv, a3 * inv);
            uint2 w; w.x = *(unsigned*)&h01; w.y = *(unsigned*)&h23;
            *(uint2*)&sm[row0 + r][c0] = w;
        } else {
            uint2 u = *(const uint2*)(xdst + (size_t)node * D + c0);
            *(uint2*)&sm[row0 + r][128 + c0] = u;
        }
    }
}

// ---------------- fused SAGE layer kernels (gather + MFMA mm, r13-proven) ----------------

__global__ __launch_bounds__(256, 4) void sage_l1_kernel(
    const __half* __restrict__ xsA, const __half* __restrict__ xdA,
    const int* __restrict__ offA, const u16* __restrict__ csrA,
    const __half* __restrict__ wTA, const float* __restrict__ bA, __half* __restrict__ outA,
    const __half* __restrict__ xsB, const __half* __restrict__ xdB,
    const int* __restrict__ offB, const u16* __restrict__ csrB,
    const __half* __restrict__ wTB, const float* __restrict__ bB, __half* __restrict__ outB)
{
    __shared__ __align__(16) __half sm[16][ROWP];
    const int s8 = blockIdx.x & 7;
    const int bank = s8 >> 2;
    const int blk = ((int)blockIdx.x >> 3) * 4 + (s8 & 3);
    if (blk >= NDIS / 16) return;
    const __half* xsrc = bank ? xsB : xsA;
    const __half* xdst = bank ? xdB : xdA;
    const int* off = bank ? offB : offA;
    const u16* csr = bank ? csrB : csrA;
    const __half* wT = bank ? wTB : wTA;
    const float* bias = bank ? bB : bA;
    __half* out16 = bank ? outB : outA;

    const int lane = threadIdx.x & 63;
    const int wid = threadIdx.x >> 6;
    const int node0 = blk * 16;

    sage_gather(xsrc, xdst, off, csr, sm, node0 + wid * 4, wid * 4, lane);
    __syncthreads();

    const int lr = lane & 15;
    const int g = lane >> 4;
    const int colbase = wid * 32;
    f4v acc0 = {0.f, 0.f, 0.f, 0.f};
    f4v acc1 = {0.f, 0.f, 0.f, 0.f};
    #pragma unroll
    for (int t = 0; t < 8; ++t) {
        h8v a = *(const h8v*)&sm[lr][t * 32 + g * 8];
        h8v b0 = *(const h8v*)(wT + (size_t)(colbase + lr) * 256 + t * 32 + g * 8);
        h8v b1 = *(const h8v*)(wT + (size_t)(colbase + 16 + lr) * 256 + t * 32 + g * 8);
        acc0 = __builtin_amdgcn_mfma_f32_16x16x32_f16(a, b0, acc0, 0, 0, 0);
        acc1 = __builtin_amdgcn_mfma_f32_16x16x32_f16(a, b1, acc1, 0, 0, 0);
    }
    #pragma unroll
    for (int reg = 0; reg < 4; ++reg) {
        int row = g * 4 + reg;
        int col0 = colbase + lr;
        int col1 = colbase + 16 + lr;
        float v0 = fmaxf(acc0[reg] + bias[col0], 0.f);
        float v1 = fmaxf(acc1[reg] + bias[col1], 0.f);
        out16[(size_t)(node0 + row) * D + col0] = __float2half_rn(v0);
        out16[(size_t)(node0 + row) * D + col1] = __float2half_rn(v1);
    }
}

__global__ __launch_bounds__(256, 4) void sage_l2_kernel(
    const __half* __restrict__ xsA, const __half* __restrict__ xdA,
    const int* __restrict__ offA, const u16* __restrict__ csrA,
    const __half* __restrict__ wTA, const float* __restrict__ bA,
    const __half* __restrict__ wdTA, const float* __restrict__ pbA, __half* __restrict__ PoutA,
    const __half* __restrict__ xsB, const __half* __restrict__ xdB,
    const int* __restrict__ offB, const u16* __restrict__ csrB,
    const __half* __restrict__ wTB, const float* __restrict__ bB,
    const __half* __restrict__ wdTB, const float* __restrict__ pbB, __half* __restrict__ PoutB)
{
    __shared__ __align__(16) __half sm[16][ROWP];
    const int s8 = blockIdx.x & 7;
    const int bank = s8 >> 2;
    const int blk = ((int)blockIdx.x >> 3) * 4 + (s8 & 3);
    if (blk >= NDIS / 16) return;
    const __half* xsrc = bank ? xsB : xsA;
    const __half* xdst = bank ? xdB : xdA;
    const int* off = bank ? offB : offA;
    const u16* csr = bank ? csrB : csrA;
    const __half* wT = bank ? wTB : wTA;
    const float* bias = bank ? bB : bA;
    const __half* wdT = bank ? wdTB : wdTA;
    const float* pb = bank ? pbB : pbA;
    __half* Pout = bank ? PoutB : PoutA;

    const int lane = threadIdx.x & 63;
    const int wid = threadIdx.x >> 6;
    const int node0 = blk * 16;

    sage_gather(xsrc, xdst, off, csr, sm, node0 + wid * 4, wid * 4, lane);
    __syncthreads();

    const int lr = lane & 15;
    const int g = lane >> 4;
    const int colbase = wid * 32;
    f4v acc0 = {0.f, 0.f, 0.f, 0.f};
    f4v acc1 = {0.f, 0.f, 0.f, 0.f};
    #pragma unroll
    for (int t = 0; t < 8; ++t) {
        h8v a = *(const h8v*)&sm[lr][t * 32 + g * 8];
        h8v b0 = *(const h8v*)(wT + (size_t)(colbase + lr) * 256 + t * 32 + g * 8);
        h8v b1 = *(const h8v*)(wT + (size_t)(colbase + 16 + lr) * 256 + t * 32 + g * 8);
        acc0 = __builtin_amdgcn_mfma_f32_16x16x32_f16(a, b0, acc0, 0, 0, 0);
        acc1 = __builtin_amdgcn_mfma_f32_16x16x32_f16(a, b1, acc1, 0, 0, 0);
    }

    __syncthreads();
    #pragma unroll
    for (int reg = 0; reg < 4; ++reg) {
        int row = g * 4 + reg;
        sm[row][colbase + lr] = __float2half_rn(acc0[reg] + bias[colbase + lr]);
        sm[row][colbase + 16 + lr] = __float2half_rn(acc1[reg] + bias[colbase + 16 + lr]);
    }
    __syncthreads();

    f4v p0 = {0.f, 0.f, 0.f, 0.f};
    f4v p1 = {0.f, 0.f, 0.f, 0.f};
    #pragma unroll
    for (int t = 0; t < 4; ++t) {
        h8v a = *(const h8v*)&sm[lr][t * 32 + g * 8];
        h8v b0 = *(const h8v*)(wdT + (size_t)(colbase + lr) * 128 + t * 32 + g * 8);
        h8v b1 = *(const h8v*)(wdT + (size_t)(colbase + 16 + lr) * 128 + t * 32 + g * 8);
        p0 = __builtin_amdgcn_mfma_f32_16x16x32_f16(a, b0, p0, 0, 0, 0);
        p1 = __builtin_amdgcn_mfma_f32_16x16x32_f16(a, b1, p1, 0, 0, 0);
    }
    #pragma unroll
    for (int reg = 0; reg < 4; ++reg) {
        int row = g * 4 + reg;
        int col0 = colbase + lr;
        int col1 = colbase + 16 + lr;
        float v0 = p0[reg] + (pb ? pb[col0] : 0.f);
        float v1 = p1[reg] + (pb ? pb[col1] : 0.f);
        Pout[(size_t)(node0 + row) * D + col0] = __float2half_rn(v0);
        Pout[(size_t)(node0 + row) * D + col1] = __float2half_rn(v1);
    }
}

// ---------------- decoder (r8-proven) ----------------

__global__ __launch_bounds__(256) void dec_gather_kernel(
    const __half* __restrict__ Pd, const __half* __restrict__ Ps,
    const int* __restrict__ row_idx, const int* __restrict__ col_idx,
    const float* __restrict__ W2, const float* __restrict__ b2,
    float* __restrict__ out, int nrows)
{
    const int lane = threadIdx.x & 63;
    const int wid = threadIdx.x >> 6;
    const int g = lane >> 4;
    const int lq = lane & 15;
    const int wave_id = blockIdx.x * 4 + wid;
    const int e0 = wave_id * 32;
    if (e0 >= nrows) return;

    const int c0 = lq * 8;
    float w2v[8];
    #pragma unroll
    for (int i = 0; i < 8; ++i) w2v[i] = W2[c0 + i];
    float b2v = b2[0];

    #pragma unroll 2
    for (int it = 0; it < 8; ++it) {
        int ei = it * 4 + g;
        int rr = e0 + ei;
        int ri = row_idx[rr];
        int ci = col_idx[rr];
        uint4 ua = *(const uint4*)(Pd + (size_t)ri * D + c0);
        uint4 ub = *(const uint4*)(Ps + (size_t)ci * D + c0);
        float fa[8], fb[8];
        h8_load(ua, fa);
        h8_load(ub, fb);
        float v = 0.f;
        #pragma unroll
        for (int i = 0; i < 8; ++i)
            v = fmaf(fmaxf(fa[i] + fb[i], 0.f), w2v[i], v);
        v += __shfl_xor(v, 1, 64);
        v += __shfl_xor(v, 2, 64);
        v += __shfl_xor(v, 4, 64);
        v += __shfl_xor(v, 8, 64);
        if (lq == 0) out[rr] = v + b2v;
    }
}

// ---------------- launcher ----------------

extern "C" void kernel_launch(void* const* d_in, const int* in_sizes, int n_in,
                              void* d_out, int out_size, void* d_ws, size_t ws_size,
                              hipStream_t stream) {
    const float* x_drug = (const float*)d_in[0];
    const float* x_dis  = (const float*)d_in[1];
    const int* ei_d2s = (const int*)d_in[2];
    const int* ei_s2d = (const int*)d_in[3];
    const int* ell    = (const int*)d_in[4];
    const float* W1l_d2s = (const float*)d_in[5];
    const float* W1r_d2s = (const float*)d_in[6];
    const float* W1l_s2d = (const float*)d_in[7];
    const float* W1r_s2d = (const float*)d_in[8];
    const float* W2l_d2s = (const float*)d_in[9];
    const float* W2r_d2s = (const float*)d_in[10];
    const float* W2l_s2d = (const float*)d_in[11];
    const float* W2r_s2d = (const float*)d_in[12];
    const float* b1_d2s = (const float*)d_in[13];
    const float* b1_s2d = (const float*)d_in[14];
    const float* b2_d2s = (const float*)d_in[15];
    const float* b2_s2d = (const float*)d_in[16];
    const float* dec_W1 = (const float*)d_in[17];
    const float* dec_b1 = (const float*)d_in[18];
    const float* dec_W2 = (const float*)d_in[19];
    const float* dec_b2 = (const float*)d_in[20];
    float* out = (float*)d_out;

    char* ws = (char*)d_ws;
    size_t o = 0;
    auto take = [&](size_t bytes) -> char* {
        char* p = ws + o;
        o += (bytes + 255) & ~(size_t)255;
        return p;
    };
    int* off_d2s = (int*)take((NDIS + 1) * sizeof(int));
    int* cnt_d2s = (int*)take(NDIS * sizeof(int));
    u16* csr_d2s = (u16*)take((size_t)EDGES * sizeof(u16));
    int* off_s2d = (int*)take((NDRUG + 1) * sizeof(int));
    int* cnt_s2d = (int*)take(NDRUG * sizeof(int));
    u16* csr_s2d = (u16*)take((size_t)EDGES * sizeof(u16));
    __half* x16_drug = (__half*)take((size_t)NDRUG * D * sizeof(__half));
    __half* x16_dis  = (__half*)take((size_t)NDIS * D * sizeof(__half));
    __half* h16_dis  = (__half*)take((size_t)NDIS * D * sizeof(__half));
    __half* h16_drug = (__half*)take((size_t)NDRUG * D * sizeof(__half));
    __half* P16_drug = (__half*)take((size_t)NDRUG * D * sizeof(__half));
    __half* P16_dis  = (__half*)take((size_t)NDIS * D * sizeof(__half));
    __half* w16 = (__half*)take((size_t)163840 * sizeof(__half));

    __half* wT_l1_d2s = w16 + 0 * 32768;
    __half* wT_l1_s2d = w16 + 1 * 32768;
    __half* wT_l2_d2s = w16 + 2 * 32768;
    __half* wT_l2_s2d = w16 + 3 * 32768;
    __half* wdT_hi    = w16 + 4 * 32768;            // dec_W1 rows 128-255 (bank A)
    __half* wdT_lo    = w16 + 4 * 32768 + 16384;    // dec_W1 rows 0-127  (bank B)

    hipMemsetAsync(cnt_d2s, 0, NDIS * sizeof(int), stream);
    hipMemsetAsync(cnt_s2d, 0, NDRUG * sizeof(int), stream);

    cvtwt_kernel<<<640, 256, 0, stream>>>(
        W1l_d2s, W1r_d2s, W1l_s2d, W1r_s2d,
        W2l_d2s, W2r_d2s, W2l_s2d, W2r_s2d, dec_W1, w16);

    cvt16x2_kernel<<<(2 * NDRUG * D / 4 + 255) / 256, 256, 0, stream>>>(
        x_drug, x16_drug, NDRUG * D / 4, x_dis, x16_dis, NDIS * D / 4);

    // CSR build: sliced hist -> scan -> sliced atomic scatter (no rank array)
    hist_sliced_kernel<<<2 * 8 * HS, 256, 0, stream>>>(
        ei_d2s + EDGES, cnt_d2s, ei_s2d + EDGES, cnt_s2d, EDGES);
    scan2_kernel<<<2, 1024, 0, stream>>>(cnt_d2s, off_d2s, cnt_s2d, off_s2d, NDIS);
    scatter_atomic_kernel<<<2 * 8 * SB, 256, 0, stream>>>(
        ei_d2s, ei_d2s + EDGES, cnt_d2s, csr_d2s,
        ei_s2d, ei_s2d + EDGES, cnt_s2d, csr_s2d, EDGES);

    // sage grids: 1250 blocks/bank, 8-padded for the %8 dir->XCD pinning
    const int SGRID = ((2 * (NDIS / 16) + 7) / 8) * 8 + 8;   // 2504

    // layer 1: bank A = d2s -> h_dis, bank B = s2d -> h_drug
    sage_l1_kernel<<<SGRID, 256, 0, stream>>>(
        x16_drug, x16_dis, off_d2s, csr_d2s, wT_l1_d2s, b1_d2s, h16_dis,
        x16_dis, x16_drug, off_s2d, csr_s2d, wT_l1_s2d, b1_s2d, h16_drug);

    // layer 2 + fused decoder projection:
    //   P_dis = z_dis @ dec_W1[128:256] + dec_b1 ; P_drug = z_drug @ dec_W1[0:128]
    sage_l2_kernel<<<SGRID, 256, 0, stream>>>(
        h16_drug, h16_dis, off_d2s, csr_d2s, wT_l2_d2s, b2_d2s, wdT_hi, dec_b1, P16_dis,
        h16_dis, h16_drug, off_s2d, csr_s2d, wT_l2_s2d, b2_s2d, wdT_lo, nullptr, P16_drug);

    // decoder
    dec_gather_kernel<<<(LROWS / 32 + 3) / 4, 256, 0, stream>>>(
        P16_drug, P16_dis, ell, ell + LROWS, dec_W2, dec_b2, out, LROWS);
}

// Round 15
// 258.422 us; speedup vs baseline: 1.2260x; 1.2260x over previous
//
#include <hip/hip_runtime.h>
#include <hip/hip_fp16.h>

#define D 128
#define NDRUG 20000
#define NDIS 20000
#define EDGES 640000
#define LROWS 200000
#define ROWP 264   // LDS row pitch in halves: 256 data + 8 pad (528B, 16B-aligned)

typedef unsigned short u16;
typedef __attribute__((ext_vector_type(8))) _Float16 h8v;
typedef __attribute__((ext_vector_type(4))) float f4v;

// ---------------- helpers ----------------

__device__ inline void h8_load(uint4 u, float f[8]) {
    float2 a = __half22float2(*(const __half2*)&u.x);
    float2 b = __half22float2(*(const __half2*)&u.y);
    float2 c = __half22float2(*(const __half2*)&u.z);
    float2 d = __half22float2(*(const __half2*)&u.w);
    f[0] = a.x; f[1] = a.y; f[2] = b.x; f[3] = b.y;
    f[4] = c.x; f[5] = c.y; f[6] = d.x; f[7] = d.y;
}

// ---------------- CSR build (r13-proven: rank2 + scan2 + sliced scatter) ----------------

__global__ __launch_bounds__(256) void rank2_kernel(
    const int* __restrict__ dA, int* __restrict__ cA, int* __restrict__ rA,
    const int* __restrict__ dB, int* __restrict__ cB, int* __restrict__ rB, int n)
{
    int i = blockIdx.x * blockDim.x + threadIdx.x;
    if (i < n) rA[i] = atomicAdd(&cA[dA[i]], 1);
    else if (i - n < n) rB[i - n] = atomicAdd(&cB[dB[i - n]], 1);
}

__global__ __launch_bounds__(1024) void scan2_kernel(int* __restrict__ c0, int* __restrict__ o0,
                                                     int* __restrict__ c1, int* __restrict__ o1,
                                                     int n) {
    int* cnt_io = (blockIdx.x == 0) ? c0 : c1;
    int* off    = (blockIdx.x == 0) ? o0 : o1;
    __shared__ int wsum[16];
    __shared__ int carry_s;
    const int tid = threadIdx.x;
    const int lane = tid & 63;
    const int wid = tid >> 6;
    if (tid == 0) { carry_s = 0; off[0] = 0; }
    __syncthreads();
    for (int start = 0; start < n; start += 1024) {
        int i = start + tid;
        int v = (i < n) ? cnt_io[i] : 0;
        int carry = carry_s;
        int s = v;
        #pragma unroll
        for (int o = 1; o < 64; o <<= 1) {
            int t = __shfl_up(s, o, 64);
            if (lane >= o) s += t;
        }
        if (lane == 63) wsum[wid] = s;
        __syncthreads();
        if (wid == 0) {
            int ws = (lane < 16) ? wsum[lane] : 0;
            #pragma unroll
            for (int o = 1; o < 16; o <<= 1) {
                int t = __shfl_up(ws, o, 64);
                if (lane >= o) ws += t;
            }
            if (lane < 16) wsum[lane] = ws;
        }
        __syncthreads();
        int woff = (wid > 0) ? wsum[wid - 1] : 0;
        int incl = s + woff + carry;
        if (i < n) {
            off[i + 1] = incl;
            cnt_io[i] = incl - v;
        }
        __syncthreads();
        if (tid == 1023) carry_s = incl;
        __syncthreads();
    }
}

#define SB 104

__global__ __launch_bounds__(256) void scatter_sliced_kernel(
    const int* __restrict__ srcA, const int* __restrict__ dstA,
    const int* __restrict__ rkA, const int* __restrict__ offA, u16* __restrict__ csrA,
    const int* __restrict__ srcB, const int* __restrict__ dstB,
    const int* __restrict__ rkB, const int* __restrict__ offB, u16* __restrict__ csrB,
    int n)
{
    int b = blockIdx.x;
    int dirB = (b >= 8 * SB);
    int bb = b - (dirB ? 8 * SB : 0);
    int s = bb & 7;
    int sub = bb >> 3;
    const int* src = dirB ? srcB : srcA;
    const int* dst = dirB ? dstB : dstA;
    const int* rk  = dirB ? rkB : rkA;
    const int* off = dirB ? offB : offA;
    u16* csr = dirB ? csrB : csrA;

    const int lo = s * 2500, hi = lo + 2500;
    const int chunk = (n + SB - 1) / SB;
    int i0 = sub * chunk;
    int i1 = i0 + chunk; i1 = i1 < n ? i1 : n;
    for (int i = i0 + threadIdx.x; i < i1; i += 256) {
        int d = dst[i];
        if (d >= lo && d < hi) {
            int pos = off[d] + rk[i];
            csr[pos] = (u16)src[i];
        }
    }
}

// ---------------- fp32 -> fp16 conversions ----------------

// both feature tables in one dispatch
__global__ __launch_bounds__(256) void cvt16x2_kernel(
    const float* __restrict__ ina, __half* __restrict__ outa, int n4a,
    const float* __restrict__ inb, __half* __restrict__ outb, int n4b)
{
    int i = blockIdx.x * blockDim.x + threadIdx.x;
    const float* in; __half* out; int idx;
    if (i < n4a) { in = ina; out = outa; idx = i; }
    else if (i - n4a < n4b) { in = inb; out = outb; idx = i - n4a; }
    else return;
    float4 v = ((const float4*)in)[idx];
    __half2 a = __floats2half2_rn(v.x, v.y);
    __half2 b = __floats2half2_rn(v.z, v.w);
    uint2 u;
    u.x = *(unsigned*)&a;
    u.y = *(unsigned*)&b;
    ((uint2*)out)[idx] = u;
}

// Transposed, stacked fp16 weights for MFMA B-operands (r13-proven).
__global__ __launch_bounds__(256) void cvtwt_kernel(
    const float* __restrict__ W1l_d2s, const float* __restrict__ W1r_d2s,
    const float* __restrict__ W1l_s2d, const float* __restrict__ W1r_s2d,
    const float* __restrict__ W2l_d2s, const float* __restrict__ W2r_d2s,
    const float* __restrict__ W2l_s2d, const float* __restrict__ W2r_s2d,
    const float* __restrict__ decW1, __half* __restrict__ out)
{
    int gid = blockIdx.x * 256 + threadIdx.x;
    float v;
    if (gid < 4 * 32768) {
        int chunk = gid >> 15;
        int r = gid & 32767;
        int col = r >> 8;
        int k = r & 255;
        const float *Wl, *Wr;
        switch (chunk) {
            case 0: Wl = W1l_d2s; Wr = W1r_d2s; break;
            case 1: Wl = W1l_s2d; Wr = W1r_s2d; break;
            case 2: Wl = W2l_d2s; Wr = W2r_d2s; break;
            default: Wl = W2l_s2d; Wr = W2r_s2d; break;
        }
        const float* src = (k < 128) ? Wl : Wr;
        v = src[(size_t)(k & 127) * D + col];
    } else {
        int r = gid - 4 * 32768;
        int chunk = r >> 14;            // 0 = hi (rows 128-255), 1 = lo
        int q = r & 16383;
        int col = q >> 7;
        int k = q & 127;
        int row = k + (chunk == 0 ? 128 : 0);
        v = decW1[(size_t)row * D + col];
    }
    out[gid] = __float2half_rn(v);
}

// ---------------- SAGE gather (r8-proven inner loop; fp16 LDS tail) ----------------
// DO NOT restructure the readlane/half-wave loop — r5/r7 variants blew up
// to 200 VGPR / 11% occupancy.

__device__ inline void sage_gather(
    const __half* __restrict__ xsrc, const __half* __restrict__ xdst,
    const int* __restrict__ off, const u16* __restrict__ csr,
    __half sm[16][ROWP], int node0, int row0, int lane)
{
    const bool hiHalf = lane >= 32;
    const int lq = lane & 31;
    const int c0 = lq * 4;          // 4 halves (8B) per lane
    for (int r = 0; r < 4; ++r) {
        int node = node0 + r;
        int e0 = off[node], e1 = off[node + 1];
        int deg = e1 - e0;
        float a0 = 0.f, a1 = 0.f, a2 = 0.f, a3 = 0.f;
        for (int base = e0; base < e1; base += 64) {
            int nv = e1 - base; nv = nv < 64 ? nv : 64;
            int myidx = 0;
            if (lane < nv) myidx = csr[base + lane];
            int npair = nv >> 1;
            int t = 0;
            for (; t + 4 <= npair; t += 4) {
                int pa0 = __builtin_amdgcn_readlane(myidx, 2 * t + 0);
                int pb0 = __builtin_amdgcn_readlane(myidx, 2 * t + 1);
                int pa1 = __builtin_amdgcn_readlane(myidx, 2 * t + 2);
                int pb1 = __builtin_amdgcn_readlane(myidx, 2 * t + 3);
                int pa2 = __builtin_amdgcn_readlane(myidx, 2 * t + 4);
                int pb2 = __builtin_amdgcn_readlane(myidx, 2 * t + 5);
                int pa3 = __builtin_amdgcn_readlane(myidx, 2 * t + 6);
                int pb3 = __builtin_amdgcn_readlane(myidx, 2 * t + 7);
                int s0 = hiHalf ? pb0 : pa0;
                int s1 = hiHalf ? pb1 : pa1;
                int s2 = hiHalf ? pb2 : pa2;
                int s3 = hiHalf ? pb3 : pa3;
                uint2 u0 = *(const uint2*)(xsrc + (size_t)s0 * D + c0);
                uint2 u1 = *(const uint2*)(xsrc + (size_t)s1 * D + c0);
                uint2 u2 = *(const uint2*)(xsrc + (size_t)s2 * D + c0);
                uint2 u3 = *(const uint2*)(xsrc + (size_t)s3 * D + c0);
                float2 t0, t1;
                t0 = __half22float2(*(const __half2*)&u0.x);
                t1 = __half22float2(*(const __half2*)&u0.y);
                a0 += t0.x; a1 += t0.y; a2 += t1.x; a3 += t1.y;
                t0 = __half22float2(*(const __half2*)&u1.x);
                t1 = __half22float2(*(const __half2*)&u1.y);
                a0 += t0.x; a1 += t0.y; a2 += t1.x; a3 += t1.y;
                t0 = __half22float2(*(const __half2*)&u2.x);
                t1 = __half22float2(*(const __half2*)&u2.y);
                a0 += t0.x; a1 += t0.y; a2 += t1.x; a3 += t1.y;
                t0 = __half22float2(*(const __half2*)&u3.x);
                t1 = __half22float2(*(const __half2*)&u3.y);
                a0 += t0.x; a1 += t0.y; a2 += t1.x; a3 += t1.y;
            }
            for (; t < npair; ++t) {
                int pa = __builtin_amdgcn_readlane(myidx, 2 * t + 0);
                int pb = __builtin_amdgcn_readlane(myidx, 2 * t + 1);
                int s = hiHalf ? pb : pa;
                uint2 u = *(const uint2*)(xsrc + (size_t)s * D + c0);
                float2 t0 = __half22float2(*(const __half2*)&u.x);
                float2 t1 = __half22float2(*(const __half2*)&u.y);
                a0 += t0.x; a1 += t0.y; a2 += t1.x; a3 += t1.y;
            }
            if (nv & 1) {
                int s = __builtin_amdgcn_readlane(myidx, nv - 1);
                if (!hiHalf) {
                    uint2 u = *(const uint2*)(xsrc + (size_t)s * D + c0);
                    float2 t0 = __half22float2(*(const __half2*)&u.x);
                    float2 t1 = __half22float2(*(const __half2*)&u.y);
                    a0 += t0.x; a1 += t0.y; a2 += t1.x; a3 += t1.y;
                }
            }
        }
        a0 += __shfl_xor(a0, 32, 64);
        a1 += __shfl_xor(a1, 32, 64);
        a2 += __shfl_xor(a2, 32, 64);
        a3 += __shfl_xor(a3, 32, 64);
        float inv = 1.0f / (float)(deg < 1 ? 1 : deg);
        if (!hiHalf) {
            __half2 h01 = __floats2half2_rn(a0 * inv, a1 * inv);
            __half2 h23 = __floats2half2_rn(a2 * inv, a3 * inv);
            uint2 w; w.x = *(unsigned*)&h01; w.y = *(unsigned*)&h23;
            *(uint2*)&sm[row0 + r][c0] = w;
        } else {
            uint2 u = *(const uint2*)(xdst + (size_t)node * D + c0);
            *(uint2*)&sm[row0 + r][128 + c0] = u;
        }
    }
}

// ---------------- fused SAGE layer kernels (gather + MFMA mm, r13-proven) ----------------
// Block = 16 nodes, 4 waves. dir->XCD pinning: blockIdx%8 in 0..3 -> bank A,
// 4..7 -> bank B. MFMA mapping (r2-verified): A row=lane&15, k=(lane>>4)*8+i;
// B col=lane&15; C/D col=lane&15, row=(lane>>4)*4+reg.

__global__ __launch_bounds__(256, 4) void sage_l1_kernel(
    const __half* __restrict__ xsA, const __half* __restrict__ xdA,
    const int* __restrict__ offA, const u16* __restrict__ csrA,
    const __half* __restrict__ wTA, const float* __restrict__ bA, __half* __restrict__ outA,
    const __half* __restrict__ xsB, const __half* __restrict__ xdB,
    const int* __restrict__ offB, const u16* __restrict__ csrB,
    const __half* __restrict__ wTB, const float* __restrict__ bB, __half* __restrict__ outB)
{
    __shared__ __align__(16) __half sm[16][ROWP];
    const int s8 = blockIdx.x & 7;
    const int bank = s8 >> 2;
    const int blk = ((int)blockIdx.x >> 3) * 4 + (s8 & 3);
    if (blk >= NDIS / 16) return;
    const __half* xsrc = bank ? xsB : xsA;
    const __half* xdst = bank ? xdB : xdA;
    const int* off = bank ? offB : offA;
    const u16* csr = bank ? csrB : csrA;
    const __half* wT = bank ? wTB : wTA;
    const float* bias = bank ? bB : bA;
    __half* out16 = bank ? outB : outA;

    const int lane = threadIdx.x & 63;
    const int wid = threadIdx.x >> 6;
    const int node0 = blk * 16;

    sage_gather(xsrc, xdst, off, csr, sm, node0 + wid * 4, wid * 4, lane);
    __syncthreads();

    const int lr = lane & 15;
    const int g = lane >> 4;
    const int colbase = wid * 32;
    f4v acc0 = {0.f, 0.f, 0.f, 0.f};
    f4v acc1 = {0.f, 0.f, 0.f, 0.f};
    #pragma unroll
    for (int t = 0; t < 8; ++t) {
        h8v a = *(const h8v*)&sm[lr][t * 32 + g * 8];
        h8v b0 = *(const h8v*)(wT + (size_t)(colbase + lr) * 256 + t * 32 + g * 8);
        h8v b1 = *(const h8v*)(wT + (size_t)(colbase + 16 + lr) * 256 + t * 32 + g * 8);
        acc0 = __builtin_amdgcn_mfma_f32_16x16x32_f16(a, b0, acc0, 0, 0, 0);
        acc1 = __builtin_amdgcn_mfma_f32_16x16x32_f16(a, b1, acc1, 0, 0, 0);
    }
    #pragma unroll
    for (int reg = 0; reg < 4; ++reg) {
        int row = g * 4 + reg;
        int col0 = colbase + lr;
        int col1 = colbase + 16 + lr;
        float v0 = fmaxf(acc0[reg] + bias[col0], 0.f);
        float v1 = fmaxf(acc1[reg] + bias[col1], 0.f);
        out16[(size_t)(node0 + row) * D + col0] = __float2half_rn(v0);
        out16[(size_t)(node0 + row) * D + col1] = __float2half_rn(v1);
    }
}

__global__ __launch_bounds__(256, 4) void sage_l2_kernel(
    const __half* __restrict__ xsA, const __half* __restrict__ xdA,
    const int* __restrict__ offA, const u16* __restrict__ csrA,
    const __half* __restrict__ wTA, const float* __restrict__ bA,
    const __half* __restrict__ wdTA, const float* __restrict__ pbA, __half* __restrict__ PoutA,
    const __half* __restrict__ xsB, const __half* __restrict__ xdB,
    const int* __restrict__ offB, const u16* __restrict__ csrB,
    const __half* __restrict__ wTB, const float* __restrict__ bB,
    const __half* __restrict__ wdTB, const float* __restrict__ pbB, __half* __restrict__ PoutB)
{
    __shared__ __align__(16) __half sm[16][ROWP];
    const int s8 = blockIdx.x & 7;
    const int bank = s8 >> 2;
    const int blk = ((int)blockIdx.x >> 3) * 4 + (s8 & 3);
    if (blk >= NDIS / 16) return;
    const __half* xsrc = bank ? xsB : xsA;
    const __half* xdst = bank ? xdB : xdA;
    const int* off = bank ? offB : offA;
    const u16* csr = bank ? csrB : csrA;
    const __half* wT = bank ? wTB : wTA;
    const float* bias = bank ? bB : bA;
    const __half* wdT = bank ? wdTB : wdTA;
    const float* pb = bank ? pbB : pbA;
    __half* Pout = bank ? PoutB : PoutA;

    const int lane = threadIdx.x & 63;
    const int wid = threadIdx.x >> 6;
    const int node0 = blk * 16;

    sage_gather(xsrc, xdst, off, csr, sm, node0 + wid * 4, wid * 4, lane);
    __syncthreads();

    const int lr = lane & 15;
    const int g = lane >> 4;
    const int colbase = wid * 32;
    f4v acc0 = {0.f, 0.f, 0.f, 0.f};
    f4v acc1 = {0.f, 0.f, 0.f, 0.f};
    #pragma unroll
    for (int t = 0; t < 8; ++t) {
        h8v a = *(const h8v*)&sm[lr][t * 32 + g * 8];
        h8v b0 = *(const h8v*)(wT + (size_t)(colbase + lr) * 256 + t * 32 + g * 8);
        h8v b1 = *(const h8v*)(wT + (size_t)(colbase + 16 + lr) * 256 + t * 32 + g * 8);
        acc0 = __builtin_amdgcn_mfma_f32_16x16x32_f16(a, b0, acc0, 0, 0, 0);
        acc1 = __builtin_amdgcn_mfma_f32_16x16x32_f16(a, b1, acc1, 0, 0, 0);
    }

    __syncthreads();
    #pragma unroll
    for (int reg = 0; reg < 4; ++reg) {
        int row = g * 4 + reg;
        sm[row][colbase + lr] = __float2half_rn(acc0[reg] + bias[colbase + lr]);
        sm[row][colbase + 16 + lr] = __float2half_rn(acc1[reg] + bias[colbase + 16 + lr]);
    }
    __syncthreads();

    f4v p0 = {0.f, 0.f, 0.f, 0.f};
    f4v p1 = {0.f, 0.f, 0.f, 0.f};
    #pragma unroll
    for (int t = 0; t < 4; ++t) {
        h8v a = *(const h8v*)&sm[lr][t * 32 + g * 8];
        h8v b0 = *(const h8v*)(wdT + (size_t)(colbase + lr) * 128 + t * 32 + g * 8);
        h8v b1 = *(const h8v*)(wdT + (size_t)(colbase + 16 + lr) * 128 + t * 32 + g * 8);
        p0 = __builtin_amdgcn_mfma_f32_16x16x32_f16(a, b0, p0, 0, 0, 0);
        p1 = __builtin_amdgcn_mfma_f32_16x16x32_f16(a, b1, p1, 0, 0, 0);
    }
    #pragma unroll
    for (int reg = 0; reg < 4; ++reg) {
        int row = g * 4 + reg;
        int col0 = colbase + lr;
        int col1 = colbase + 16 + lr;
        float v0 = p0[reg] + (pb ? pb[col0] : 0.f);
        float v1 = p1[reg] + (pb ? pb[col1] : 0.f);
        Pout[(size_t)(node0 + row) * D + col0] = __float2half_rn(v0);
        Pout[(size_t)(node0 + row) * D + col1] = __float2half_rn(v1);
    }
}

// ---------------- decoder (r8-proven) ----------------

__global__ __launch_bounds__(256) void dec_gather_kernel(
    const __half* __restrict__ Pd, const __half* __restrict__ Ps,
    const int* __restrict__ row_idx, const int* __restrict__ col_idx,
    const float* __restrict__ W2, const float* __restrict__ b2,
    float* __restrict__ out, int nrows)
{
    const int lane = threadIdx.x & 63;
    const int wid = threadIdx.x >> 6;
    const int g = lane >> 4;
    const int lq = lane & 15;
    const int wave_id = blockIdx.x * 4 + wid;
    const int e0 = wave_id * 32;
    if (e0 >= nrows) return;

    const int c0 = lq * 8;
    float w2v[8];
    #pragma unroll
    for (int i = 0; i < 8; ++i) w2v[i] = W2[c0 + i];
    float b2v = b2[0];

    #pragma unroll 2
    for (int it = 0; it < 8; ++it) {
        int ei = it * 4 + g;
        int rr = e0 + ei;
        int ri = row_idx[rr];
        int ci = col_idx[rr];
        uint4 ua = *(const uint4*)(Pd + (size_t)ri * D + c0);
        uint4 ub = *(const uint4*)(Ps + (size_t)ci * D + c0);
        float fa[8], fb[8];
        h8_load(ua, fa);
        h8_load(ub, fb);
        float v = 0.f;
        #pragma unroll
        for (int i = 0; i < 8; ++i)
            v = fmaf(fmaxf(fa[i] + fb[i], 0.f), w2v[i], v);
        v += __shfl_xor(v, 1, 64);
        v += __shfl_xor(v, 2, 64);
        v += __shfl_xor(v, 4, 64);
        v += __shfl_xor(v, 8, 64);
        if (lq == 0) out[rr] = v + b2v;
    }
}

// ---------------- launcher ----------------

extern "C" void kernel_launch(void* const* d_in, const int* in_sizes, int n_in,
                              void* d_out, int out_size, void* d_ws, size_t ws_size,
                              hipStream_t stream) {
    const float* x_drug = (const float*)d_in[0];
    const float* x_dis  = (const float*)d_in[1];
    const int* ei_d2s = (const int*)d_in[2];
    const int* ei_s2d = (const int*)d_in[3];
    const int* ell    = (const int*)d_in[4];
    const float* W1l_d2s = (const float*)d_in[5];
    const float* W1r_d2s = (const float*)d_in[6];
    const float* W1l_s2d = (const float*)d_in[7];
    const float* W1r_s2d = (const float*)d_in[8];
    const float* W2l_d2s = (const float*)d_in[9];
    const float* W2r_d2s = (const float*)d_in[10];
    const float* W2l_s2d = (const float*)d_in[11];
    const float* W2r_s2d = (const float*)d_in[12];
    const float* b1_d2s = (const float*)d_in[13];
    const float* b1_s2d = (const float*)d_in[14];
    const float* b2_d2s = (const float*)d_in[15];
    const float* b2_s2d = (const float*)d_in[16];
    const float* dec_W1 = (const float*)d_in[17];
    const float* dec_b1 = (const float*)d_in[18];
    const float* dec_W2 = (const float*)d_in[19];
    const float* dec_b2 = (const float*)d_in[20];
    float* out = (float*)d_out;

    char* ws = (char*)d_ws;
    size_t o = 0;
    auto take = [&](size_t bytes) -> char* {
        char* p = ws + o;
        o += (bytes + 255) & ~(size_t)255;
        return p;
    };
    int* off_d2s = (int*)take((NDIS + 1) * sizeof(int));
    int* cnt_d2s = (int*)take(NDIS * sizeof(int));
    u16* csr_d2s = (u16*)take((size_t)EDGES * sizeof(u16));
    int* rk_d2s  = (int*)take((size_t)EDGES * sizeof(int));
    int* off_s2d = (int*)take((NDRUG + 1) * sizeof(int));
    int* cnt_s2d = (int*)take(NDRUG * sizeof(int));
    u16* csr_s2d = (u16*)take((size_t)EDGES * sizeof(u16));
    int* rk_s2d  = (int*)take((size_t)EDGES * sizeof(int));
    __half* x16_drug = (__half*)take((size_t)NDRUG * D * sizeof(__half));
    __half* x16_dis  = (__half*)take((size_t)NDIS * D * sizeof(__half));
    __half* h16_dis  = (__half*)take((size_t)NDIS * D * sizeof(__half));
    __half* h16_drug = (__half*)take((size_t)NDRUG * D * sizeof(__half));
    __half* P16_drug = (__half*)take((size_t)NDRUG * D * sizeof(__half));
    __half* P16_dis  = (__half*)take((size_t)NDIS * D * sizeof(__half));
    __half* w16 = (__half*)take((size_t)163840 * sizeof(__half));

    __half* wT_l1_d2s = w16 + 0 * 32768;
    __half* wT_l1_s2d = w16 + 1 * 32768;
    __half* wT_l2_d2s = w16 + 2 * 32768;
    __half* wT_l2_s2d = w16 + 3 * 32768;
    __half* wdT_hi    = w16 + 4 * 32768;            // dec_W1 rows 128-255 (bank A)
    __half* wdT_lo    = w16 + 4 * 32768 + 16384;    // dec_W1 rows 0-127  (bank B)

    hipMemsetAsync(cnt_d2s, 0, NDIS * sizeof(int), stream);
    hipMemsetAsync(cnt_s2d, 0, NDRUG * sizeof(int), stream);

    cvtwt_kernel<<<640, 256, 0, stream>>>(
        W1l_d2s, W1r_d2s, W1l_s2d, W1r_s2d,
        W2l_d2s, W2r_d2s, W2l_s2d, W2r_s2d, dec_W1, w16);

    cvt16x2_kernel<<<(2 * NDRUG * D / 4 + 255) / 256, 256, 0, stream>>>(
        x_drug, x16_drug, NDRUG * D / 4, x_dis, x16_dis, NDIS * D / 4);

    // CSR build (r13-proven): rank2 -> scan2 -> sliced scatter
    const int EB2 = (2 * EDGES + 255) / 256;
    rank2_kernel<<<EB2, 256, 0, stream>>>(ei_d2s + EDGES, cnt_d2s, rk_d2s,
                                          ei_s2d + EDGES, cnt_s2d, rk_s2d, EDGES);
    scan2_kernel<<<2, 1024, 0, stream>>>(cnt_d2s, off_d2s, cnt_s2d, off_s2d, NDIS);
    scatter_sliced_kernel<<<2 * 8 * SB, 256, 0, stream>>>(
        ei_d2s, ei_d2s + EDGES, rk_d2s, off_d2s, csr_d2s,
        ei_s2d, ei_s2d + EDGES, rk_s2d, off_s2d, csr_s2d, EDGES);

    // sage grids: 1250 blocks/bank, 8-padded for the %8 dir->XCD pinning
    const int SGRID = ((2 * (NDIS / 16) + 7) / 8) * 8 + 8;   // 2504

    // layer 1: bank A = d2s -> h_dis, bank B = s2d -> h_drug
    sage_l1_kernel<<<SGRID, 256, 0, stream>>>(
        x16_drug, x16_dis, off_d2s, csr_d2s, wT_l1_d2s, b1_d2s, h16_dis,
        x16_dis, x16_drug, off_s2d, csr_s2d, wT_l1_s2d, b1_s2d, h16_drug);

    // layer 2 + fused decoder projection:
    //   P_dis = z_dis @ dec_W1[128:256] + dec_b1 ; P_drug = z_drug @ dec_W1[0:128]
    sage_l2_kernel<<<SGRID, 256, 0, stream>>>(
        h16_drug, h16_dis, off_d2s, csr_d2s, wT_l2_d2s, b2_d2s, wdT_hi, dec_b1, P16_dis,
        h16_dis, h16_drug, off_s2d, csr_s2d, wT_l2_s2d, b2_s2d, wdT_lo, nullptr, P16_drug);

    // decoder
    dec_gather_kernel<<<(LROWS / 32 + 3) / 4, 256, 0, stream>>>(
        P16_drug, P16_dis, ell, ell + LROWS, dec_W2, dec_b2, out, LROWS);
}

// Round 16
// 258.099 us; speedup vs baseline: 1.2276x; 1.0012x over previous
//
#include <hip/hip_runtime.h>
#include <hip/hip_fp16.h>

#define D 128
#define NDRUG 20000
#define NDIS 20000
#define EDGES 640000
#define LROWS 200000
#define ROWP 264   // LDS row pitch in halves: 256 data + 8 pad (528B, 16B-aligned)

typedef unsigned short u16;
typedef __attribute__((ext_vector_type(8))) _Float16 h8v;
typedef __attribute__((ext_vector_type(4))) _Float16 h4v;
typedef __attribute__((ext_vector_type(4))) float f4v;

// ---------------- helpers ----------------

__device__ inline void h8_load(uint4 u, float f[8]) {
    float2 a = __half22float2(*(const __half2*)&u.x);
    float2 b = __half22float2(*(const __half2*)&u.y);
    float2 c = __half22float2(*(const __half2*)&u.z);
    float2 d = __half22float2(*(const __half2*)&u.w);
    f[0] = a.x; f[1] = a.y; f[2] = b.x; f[3] = b.y;
    f[4] = c.x; f[5] = c.y; f[6] = d.x; f[7] = d.y;
}

// ---------------- CSR build (r13-proven: rank2 + scan2 + sliced scatter) ----------------

__global__ __launch_bounds__(256) void rank2_kernel(
    const int* __restrict__ dA, int* __restrict__ cA, int* __restrict__ rA,
    const int* __restrict__ dB, int* __restrict__ cB, int* __restrict__ rB, int n)
{
    int i = blockIdx.x * blockDim.x + threadIdx.x;
    if (i < n) rA[i] = atomicAdd(&cA[dA[i]], 1);
    else if (i - n < n) rB[i - n] = atomicAdd(&cB[dB[i - n]], 1);
}

__global__ __launch_bounds__(1024) void scan2_kernel(int* __restrict__ c0, int* __restrict__ o0,
                                                     int* __restrict__ c1, int* __restrict__ o1,
                                                     int n) {
    int* cnt_io = (blockIdx.x == 0) ? c0 : c1;
    int* off    = (blockIdx.x == 0) ? o0 : o1;
    __shared__ int wsum[16];
    __shared__ int carry_s;
    const int tid = threadIdx.x;
    const int lane = tid & 63;
    const int wid = tid >> 6;
    if (tid == 0) { carry_s = 0; off[0] = 0; }
    __syncthreads();
    for (int start = 0; start < n; start += 1024) {
        int i = start + tid;
        int v = (i < n) ? cnt_io[i] : 0;
        int carry = carry_s;
        int s = v;
        #pragma unroll
        for (int o = 1; o < 64; o <<= 1) {
            int t = __shfl_up(s, o, 64);
            if (lane >= o) s += t;
        }
        if (lane == 63) wsum[wid] = s;
        __syncthreads();
        if (wid == 0) {
            int ws = (lane < 16) ? wsum[lane] : 0;
            #pragma unroll
            for (int o = 1; o < 16; o <<= 1) {
                int t = __shfl_up(ws, o, 64);
                if (lane >= o) ws += t;
            }
            if (lane < 16) wsum[lane] = ws;
        }
        __syncthreads();
        int woff = (wid > 0) ? wsum[wid - 1] : 0;
        int incl = s + woff + carry;
        if (i < n) {
            off[i + 1] = incl;
            cnt_io[i] = incl - v;
        }
        __syncthreads();
        if (tid == 1023) carry_s = incl;
        __syncthreads();
    }
}

#define SB 104

__global__ __launch_bounds__(256) void scatter_sliced_kernel(
    const int* __restrict__ srcA, const int* __restrict__ dstA,
    const int* __restrict__ rkA, const int* __restrict__ offA, u16* __restrict__ csrA,
    const int* __restrict__ srcB, const int* __restrict__ dstB,
    const int* __restrict__ rkB, const int* __restrict__ offB, u16* __restrict__ csrB,
    int n)
{
    int b = blockIdx.x;
    int dirB = (b >= 8 * SB);
    int bb = b - (dirB ? 8 * SB : 0);
    int s = bb & 7;
    int sub = bb >> 3;
    const int* src = dirB ? srcB : srcA;
    const int* dst = dirB ? dstB : dstA;
    const int* rk  = dirB ? rkB : rkA;
    const int* off = dirB ? offB : offA;
    u16* csr = dirB ? csrB : csrA;

    const int lo = s * 2500, hi = lo + 2500;
    const int chunk = (n + SB - 1) / SB;
    int i0 = sub * chunk;
    int i1 = i0 + chunk; i1 = i1 < n ? i1 : n;
    for (int i = i0 + threadIdx.x; i < i1; i += 256) {
        int d = dst[i];
        if (d >= lo && d < hi) {
            int pos = off[d] + rk[i];
            csr[pos] = (u16)src[i];
        }
    }
}

// ---------------- fp32 -> fp16 conversions ----------------

__global__ __launch_bounds__(256) void cvt16x2_kernel(
    const float* __restrict__ ina, __half* __restrict__ outa, int n4a,
    const float* __restrict__ inb, __half* __restrict__ outb, int n4b)
{
    int i = blockIdx.x * blockDim.x + threadIdx.x;
    const float* in; __half* out; int idx;
    if (i < n4a) { in = ina; out = outa; idx = i; }
    else if (i - n4a < n4b) { in = inb; out = outb; idx = i - n4a; }
    else return;
    float4 v = ((const float4*)in)[idx];
    __half2 a = __floats2half2_rn(v.x, v.y);
    __half2 b = __floats2half2_rn(v.z, v.w);
    uint2 u;
    u.x = *(unsigned*)&a;
    u.y = *(unsigned*)&b;
    ((uint2*)out)[idx] = u;
}

// Transposed, stacked fp16 weights for MFMA B-operands (r13-proven).
__global__ __launch_bounds__(256) void cvtwt_kernel(
    const float* __restrict__ W1l_d2s, const float* __restrict__ W1r_d2s,
    const float* __restrict__ W1l_s2d, const float* __restrict__ W1r_s2d,
    const float* __restrict__ W2l_d2s, const float* __restrict__ W2r_d2s,
    const float* __restrict__ W2l_s2d, const float* __restrict__ W2r_s2d,
    const float* __restrict__ decW1, __half* __restrict__ out)
{
    int gid = blockIdx.x * 256 + threadIdx.x;
    float v;
    if (gid < 4 * 32768) {
        int chunk = gid >> 15;
        int r = gid & 32767;
        int col = r >> 8;
        int k = r & 255;
        const float *Wl, *Wr;
        switch (chunk) {
            case 0: Wl = W1l_d2s; Wr = W1r_d2s; break;
            case 1: Wl = W1l_s2d; Wr = W1r_s2d; break;
            case 2: Wl = W2l_d2s; Wr = W2r_d2s; break;
            default: Wl = W2l_s2d; Wr = W2r_s2d; break;
        }
        const float* src = (k < 128) ? Wl : Wr;
        v = src[(size_t)(k & 127) * D + col];
    } else {
        int r = gid - 4 * 32768;
        int chunk = r >> 14;            // 0 = hi (rows 128-255), 1 = lo
        int q = r & 16383;
        int col = q >> 7;
        int k = q & 127;
        int row = k + (chunk == 0 ? 128 : 0);
        v = decW1[(size_t)row * D + col];
    }
    out[gid] = __float2half_rn(v);
}

// ---------------- SAGE gather (r8-proven loop; fp16 packed accumulation) ----------------
// DO NOT restructure the readlane/half-wave loop — r5/r7 variants blew up
// to 200 VGPR / 11% occupancy. r16 change: accumulate in packed fp16
// (v_pk_add_f16, 2 ops/uint2 vs 8 cvt+add) — each lane-half sums <=~32
// O(1) values, error ~ulp*sqrt(n) << threshold.

__device__ inline void sage_gather(
    const __half* __restrict__ xsrc, const __half* __restrict__ xdst,
    const int* __restrict__ off, const u16* __restrict__ csr,
    __half sm[16][ROWP], int node0, int row0, int lane)
{
    const bool hiHalf = lane >= 32;
    const int lq = lane & 31;
    const int c0 = lq * 4;          // 4 halves (8B) per lane
    for (int r = 0; r < 4; ++r) {
        int node = node0 + r;
        int e0 = off[node], e1 = off[node + 1];
        int deg = e1 - e0;
        h4v acc = {(_Float16)0, (_Float16)0, (_Float16)0, (_Float16)0};
        for (int base = e0; base < e1; base += 64) {
            int nv = e1 - base; nv = nv < 64 ? nv : 64;
            int myidx = 0;
            if (lane < nv) myidx = csr[base + lane];
            int npair = nv >> 1;
            int t = 0;
            for (; t + 4 <= npair; t += 4) {
                int pa0 = __builtin_amdgcn_readlane(myidx, 2 * t + 0);
                int pb0 = __builtin_amdgcn_readlane(myidx, 2 * t + 1);
                int pa1 = __builtin_amdgcn_readlane(myidx, 2 * t + 2);
                int pb1 = __builtin_amdgcn_readlane(myidx, 2 * t + 3);
                int pa2 = __builtin_amdgcn_readlane(myidx, 2 * t + 4);
                int pb2 = __builtin_amdgcn_readlane(myidx, 2 * t + 5);
                int pa3 = __builtin_amdgcn_readlane(myidx, 2 * t + 6);
                int pb3 = __builtin_amdgcn_readlane(myidx, 2 * t + 7);
                int s0 = hiHalf ? pb0 : pa0;
                int s1 = hiHalf ? pb1 : pa1;
                int s2 = hiHalf ? pb2 : pa2;
                int s3 = hiHalf ? pb3 : pa3;
                h4v v0 = *(const h4v*)(xsrc + (size_t)s0 * D + c0);
                h4v v1 = *(const h4v*)(xsrc + (size_t)s1 * D + c0);
                h4v v2 = *(const h4v*)(xsrc + (size_t)s2 * D + c0);
                h4v v3 = *(const h4v*)(xsrc + (size_t)s3 * D + c0);
                acc += v0;
                acc += v1;
                acc += v2;
                acc += v3;
            }
            for (; t < npair; ++t) {
                int pa = __builtin_amdgcn_readlane(myidx, 2 * t + 0);
                int pb = __builtin_amdgcn_readlane(myidx, 2 * t + 1);
                int s = hiHalf ? pb : pa;
                h4v v = *(const h4v*)(xsrc + (size_t)s * D + c0);
                acc += v;
            }
            if (nv & 1) {
                int s = __builtin_amdgcn_readlane(myidx, nv - 1);
                if (!hiHalf) {
                    h4v v = *(const h4v*)(xsrc + (size_t)s * D + c0);
                    acc += v;
                }
            }
        }
        // combine half-waves: 2 packed shuffles + packed add
        uint2 pk = *(uint2*)&acc;
        uint2 other;
        other.x = __shfl_xor((int)pk.x, 32, 64);
        other.y = __shfl_xor((int)pk.y, 32, 64);
        acc += *(h4v*)&other;
        float inv = 1.0f / (float)(deg < 1 ? 1 : deg);
        if (!hiHalf) {
            __half2 h01 = __floats2half2_rn((float)acc[0] * inv, (float)acc[1] * inv);
            __half2 h23 = __floats2half2_rn((float)acc[2] * inv, (float)acc[3] * inv);
            uint2 w; w.x = *(unsigned*)&h01; w.y = *(unsigned*)&h23;
            *(uint2*)&sm[row0 + r][c0] = w;
        } else {
            uint2 u = *(const uint2*)(xdst + (size_t)node * D + c0);
            *(uint2*)&sm[row0 + r][128 + c0] = u;
        }
    }
}

// ---------------- fused SAGE layer kernels (gather + MFMA mm, r13-proven) ----------------
// Block = 16 nodes, 4 waves. dir->XCD pinning: blockIdx%8 in 0..3 -> bank A,
// 4..7 -> bank B. MFMA mapping (r2-verified): A row=lane&15, k=(lane>>4)*8+i;
// B col=lane&15; C/D col=lane&15, row=(lane>>4)*4+reg.

__global__ __launch_bounds__(256, 4) void sage_l1_kernel(
    const __half* __restrict__ xsA, const __half* __restrict__ xdA,
    const int* __restrict__ offA, const u16* __restrict__ csrA,
    const __half* __restrict__ wTA, const float* __restrict__ bA, __half* __restrict__ outA,
    const __half* __restrict__ xsB, const __half* __restrict__ xdB,
    const int* __restrict__ offB, const u16* __restrict__ csrB,
    const __half* __restrict__ wTB, const float* __restrict__ bB, __half* __restrict__ outB)
{
    __shared__ __align__(16) __half sm[16][ROWP];
    const int s8 = blockIdx.x & 7;
    const int bank = s8 >> 2;
    const int blk = ((int)blockIdx.x >> 3) * 4 + (s8 & 3);
    if (blk >= NDIS / 16) return;
    const __half* xsrc = bank ? xsB : xsA;
    const __half* xdst = bank ? xdB : xdA;
    const int* off = bank ? offB : offA;
    const u16* csr = bank ? csrB : csrA;
    const __half* wT = bank ? wTB : wTA;
    const float* bias = bank ? bB : bA;
    __half* out16 = bank ? outB : outA;

    const int lane = threadIdx.x & 63;
    const int wid = threadIdx.x >> 6;
    const int node0 = blk * 16;

    sage_gather(xsrc, xdst, off, csr, sm, node0 + wid * 4, wid * 4, lane);
    __syncthreads();

    const int lr = lane & 15;
    const int g = lane >> 4;
    const int colbase = wid * 32;
    f4v acc0 = {0.f, 0.f, 0.f, 0.f};
    f4v acc1 = {0.f, 0.f, 0.f, 0.f};
    #pragma unroll
    for (int t = 0; t < 8; ++t) {
        h8v a = *(const h8v*)&sm[lr][t * 32 + g * 8];
        h8v b0 = *(const h8v*)(wT + (size_t)(colbase + lr) * 256 + t * 32 + g * 8);
        h8v b1 = *(const h8v*)(wT + (size_t)(colbase + 16 + lr) * 256 + t * 32 + g * 8);
        acc0 = __builtin_amdgcn_mfma_f32_16x16x32_f16(a, b0, acc0, 0, 0, 0);
        acc1 = __builtin_amdgcn_mfma_f32_16x16x32_f16(a, b1, acc1, 0, 0, 0);
    }
    #pragma unroll
    for (int reg = 0; reg < 4; ++reg) {
        int row = g * 4 + reg;
        int col0 = colbase + lr;
        int col1 = colbase + 16 + lr;
        float v0 = fmaxf(acc0[reg] + bias[col0], 0.f);
        float v1 = fmaxf(acc1[reg] + bias[col1], 0.f);
        out16[(size_t)(node0 + row) * D + col0] = __float2half_rn(v0);
        out16[(size_t)(node0 + row) * D + col1] = __float2half_rn(v1);
    }
}

__global__ __launch_bounds__(256, 4) void sage_l2_kernel(
    const __half* __restrict__ xsA, const __half* __restrict__ xdA,
    const int* __restrict__ offA, const u16* __restrict__ csrA,
    const __half* __restrict__ wTA, const float* __restrict__ bA,
    const __half* __restrict__ wdTA, const float* __restrict__ pbA, __half* __restrict__ PoutA,
    const __half* __restrict__ xsB, const __half* __restrict__ xdB,
    const int* __restrict__ offB, const u16* __restrict__ csrB,
    const __half* __restrict__ wTB, const float* __restrict__ bB,
    const __half* __restrict__ wdTB, const float* __restrict__ pbB, __half* __restrict__ PoutB)
{
    __shared__ __align__(16) __half sm[16][ROWP];
    const int s8 = blockIdx.x & 7;
    const int bank = s8 >> 2;
    const int blk = ((int)blockIdx.x >> 3) * 4 + (s8 & 3);
    if (blk >= NDIS / 16) return;
    const __half* xsrc = bank ? xsB : xsA;
    const __half* xdst = bank ? xdB : xdA;
    const int* off = bank ? offB : offA;
    const u16* csr = bank ? csrB : csrA;
    const __half* wT = bank ? wTB : wTA;
    const float* bias = bank ? bB : bA;
    const __half* wdT = bank ? wdTB : wdTA;
    const float* pb = bank ? pbB : pbA;
    __half* Pout = bank ? PoutB : PoutA;

    const int lane = threadIdx.x & 63;
    const int wid = threadIdx.x >> 6;
    const int node0 = blk * 16;

    sage_gather(xsrc, xdst, off, csr, sm, node0 + wid * 4, wid * 4, lane);
    __syncthreads();

    const int lr = lane & 15;
    const int g = lane >> 4;
    const int colbase = wid * 32;
    f4v acc0 = {0.f, 0.f, 0.f, 0.f};
    f4v acc1 = {0.f, 0.f, 0.f, 0.f};
    #pragma unroll
    for (int t = 0; t < 8; ++t) {
        h8v a = *(const h8v*)&sm[lr][t * 32 + g * 8];
        h8v b0 = *(const h8v*)(wT + (size_t)(colbase + lr) * 256 + t * 32 + g * 8);
        h8v b1 = *(const h8v*)(wT + (size_t)(colbase + 16 + lr) * 256 + t * 32 + g * 8);
        acc0 = __builtin_amdgcn_mfma_f32_16x16x32_f16(a, b0, acc0, 0, 0, 0);
        acc1 = __builtin_amdgcn_mfma_f32_16x16x32_f16(a, b1, acc1, 0, 0, 0);
    }

    __syncthreads();
    #pragma unroll
    for (int reg = 0; reg < 4; ++reg) {
        int row = g * 4 + reg;
        sm[row][colbase + lr] = __float2half_rn(acc0[reg] + bias[colbase + lr]);
        sm[row][colbase + 16 + lr] = __float2half_rn(acc1[reg] + bias[colbase + 16 + lr]);
    }
    __syncthreads();

    f4v p0 = {0.f, 0.f, 0.f, 0.f};
    f4v p1 = {0.f, 0.f, 0.f, 0.f};
    #pragma unroll
    for (int t = 0; t < 4; ++t) {
        h8v a = *(const h8v*)&sm[lr][t * 32 + g * 8];
        h8v b0 = *(const h8v*)(wdT + (size_t)(colbase + lr) * 128 + t * 32 + g * 8);
        h8v b1 = *(const h8v*)(wdT + (size_t)(colbase + 16 + lr) * 128 + t * 32 + g * 8);
        p0 = __builtin_amdgcn_mfma_f32_16x16x32_f16(a, b0, p0, 0, 0, 0);
        p1 = __builtin_amdgcn_mfma_f32_16x16x32_f16(a, b1, p1, 0, 0, 0);
    }
    #pragma unroll
    for (int reg = 0; reg < 4; ++reg) {
        int row = g * 4 + reg;
        int col0 = colbase + lr;
        int col1 = colbase + 16 + lr;
        float v0 = p0[reg] + (pb ? pb[col0] : 0.f);
        float v1 = p1[reg] + (pb ? pb[col1] : 0.f);
        Pout[(size_t)(node0 + row) * D + col0] = __float2half_rn(v0);
        Pout[(size_t)(node0 + row) * D + col1] = __float2half_rn(v1);
    }
}

// ---------------- decoder (r8-proven) ----------------

__global__ __launch_bounds__(256) void dec_gather_kernel(
    const __half* __restrict__ Pd, const __half* __restrict__ Ps,
    const int* __restrict__ row_idx, const int* __restrict__ col_idx,
    const float* __restrict__ W2, const float* __restrict__ b2,
    float* __restrict__ out, int nrows)
{
    const int lane = threadIdx.x & 63;
    const int wid = threadIdx.x >> 6;
    const int g = lane >> 4;
    const int lq = lane & 15;
    const int wave_id = blockIdx.x * 4 + wid;
    const int e0 = wave_id * 32;
    if (e0 >= nrows) return;

    const int c0 = lq * 8;
    float w2v[8];
    #pragma unroll
    for (int i = 0; i < 8; ++i) w2v[i] = W2[c0 + i];
    float b2v = b2[0];

    #pragma unroll 2
    for (int it = 0; it < 8; ++it) {
        int ei = it * 4 + g;
        int rr = e0 + ei;
        int ri = row_idx[rr];
        int ci = col_idx[rr];
        uint4 ua = *(const uint4*)(Pd + (size_t)ri * D + c0);
        uint4 ub = *(const uint4*)(Ps + (size_t)ci * D + c0);
        float fa[8], fb[8];
        h8_load(ua, fa);
        h8_load(ub, fb);
        float v = 0.f;
        #pragma unroll
        for (int i = 0; i < 8; ++i)
            v = fmaf(fmaxf(fa[i] + fb[i], 0.f), w2v[i], v);
        v += __shfl_xor(v, 1, 64);
        v += __shfl_xor(v, 2, 64);
        v += __shfl_xor(v, 4, 64);
        v += __shfl_xor(v, 8, 64);
        if (lq == 0) out[rr] = v + b2v;
    }
}

// ---------------- launcher ----------------

extern "C" void kernel_launch(void* const* d_in, const int* in_sizes, int n_in,
                              void* d_out, int out_size, void* d_ws, size_t ws_size,
                              hipStream_t stream) {
    const float* x_drug = (const float*)d_in[0];
    const float* x_dis  = (const float*)d_in[1];
    const int* ei_d2s = (const int*)d_in[2];
    const int* ei_s2d = (const int*)d_in[3];
    const int* ell    = (const int*)d_in[4];
    const float* W1l_d2s = (const float*)d_in[5];
    const float* W1r_d2s = (const float*)d_in[6];
    const float* W1l_s2d = (const float*)d_in[7];
    const float* W1r_s2d = (const float*)d_in[8];
    const float* W2l_d2s = (const float*)d_in[9];
    const float* W2r_d2s = (const float*)d_in[10];
    const float* W2l_s2d = (const float*)d_in[11];
    const float* W2r_s2d = (const float*)d_in[12];
    const float* b1_d2s = (const float*)d_in[13];
    const float* b1_s2d = (const float*)d_in[14];
    const float* b2_d2s = (const float*)d_in[15];
    const float* b2_s2d = (const float*)d_in[16];
    const float* dec_W1 = (const float*)d_in[17];
    const float* dec_b1 = (const float*)d_in[18];
    const float* dec_W2 = (const float*)d_in[19];
    const float* dec_b2 = (const float*)d_in[20];
    float* out = (float*)d_out;

    char* ws = (char*)d_ws;
    size_t o = 0;
    auto take = [&](size_t bytes) -> char* {
        char* p = ws + o;
        o += (bytes + 255) & ~(size_t)255;
        return p;
    };
    int* off_d2s = (int*)take((NDIS + 1) * sizeof(int));
    int* cnt_d2s = (int*)take(NDIS * sizeof(int));
    u16* csr_d2s = (u16*)take((size_t)EDGES * sizeof(u16));
    int* rk_d2s  = (int*)take((size_t)EDGES * sizeof(int));
    int* off_s2d = (int*)take((NDRUG + 1) * sizeof(int));
    int* cnt_s2d = (int*)take(NDRUG * sizeof(int));
    u16* csr_s2d = (u16*)take((size_t)EDGES * sizeof(u16));
    int* rk_s2d  = (int*)take((size_t)EDGES * sizeof(int));
    __half* x16_drug = (__half*)take((size_t)NDRUG * D * sizeof(__half));
    __half* x16_dis  = (__half*)take((size_t)NDIS * D * sizeof(__half));
    __half* h16_dis  = (__half*)take((size_t)NDIS * D * sizeof(__half));
    __half* h16_drug = (__half*)take((size_t)NDRUG * D * sizeof(__half));
    __half* P16_drug = (__half*)take((size_t)NDRUG * D * sizeof(__half));
    __half* P16_dis  = (__half*)take((size_t)NDIS * D * sizeof(__half));
    __half* w16 = (__half*)take((size_t)163840 * sizeof(__half));

    __half* wT_l1_d2s = w16 + 0 * 32768;
    __half* wT_l1_s2d = w16 + 1 * 32768;
    __half* wT_l2_d2s = w16 + 2 * 32768;
    __half* wT_l2_s2d = w16 + 3 * 32768;
    __half* wdT_hi    = w16 + 4 * 32768;            // dec_W1 rows 128-255 (bank A)
    __half* wdT_lo    = w16 + 4 * 32768 + 16384;    // dec_W1 rows 0-127  (bank B)

    hipMemsetAsync(cnt_d2s, 0, NDIS * sizeof(int), stream);
    hipMemsetAsync(cnt_s2d, 0, NDRUG * sizeof(int), stream);

    cvtwt_kernel<<<640, 256, 0, stream>>>(
        W1l_d2s, W1r_d2s, W1l_s2d, W1r_s2d,
        W2l_d2s, W2r_d2s, W2l_s2d, W2r_s2d, dec_W1, w16);

    cvt16x2_kernel<<<(2 * NDRUG * D / 4 + 255) / 256, 256, 0, stream>>>(
        x_drug, x16_drug, NDRUG * D / 4, x_dis, x16_dis, NDIS * D / 4);

    // CSR build (r13-proven): rank2 -> scan2 -> sliced scatter
    const int EB2 = (2 * EDGES + 255) / 256;
    rank2_kernel<<<EB2, 256, 0, stream>>>(ei_d2s + EDGES, cnt_d2s, rk_d2s,
                                          ei_s2d + EDGES, cnt_s2d, rk_s2d, EDGES);
    scan2_kernel<<<2, 1024, 0, stream>>>(cnt_d2s, off_d2s, cnt_s2d, off_s2d, NDIS);
    scatter_sliced_kernel<<<2 * 8 * SB, 256, 0, stream>>>(
        ei_d2s, ei_d2s + EDGES, rk_d2s, off_d2s, csr_d2s,
        ei_s2d, ei_s2d + EDGES, rk_s2d, off_s2d, csr_s2d, EDGES);

    // sage grids: 1250 blocks/bank, 8-padded for the %8 dir->XCD pinning
    const int SGRID = ((2 * (NDIS / 16) + 7) / 8) * 8 + 8;   // 2504

    // layer 1: bank A = d2s -> h_dis, bank B = s2d -> h_drug
    sage_l1_kernel<<<SGRID, 256, 0, stream>>>(
        x16_drug, x16_dis, off_d2s, csr_d2s, wT_l1_d2s, b1_d2s, h16_dis,
        x16_dis, x16_drug, off_s2d, csr_s2d, wT_l1_s2d, b1_s2d, h16_drug);

    // layer 2 + fused decoder projection:
    //   P_dis = z_dis @ dec_W1[128:256] + dec_b1 ; P_drug = z_drug @ dec_W1[0:128]
    sage_l2_kernel<<<SGRID, 256, 0, stream>>>(
        h16_drug, h16_dis, off_d2s, csr_d2s, wT_l2_d2s, b2_d2s, wdT_hi, dec_b1, P16_dis,
        h16_dis, h16_drug, off_s2d, csr_s2d, wT_l2_s2d, b2_s2d, wdT_lo, nullptr, P16_drug);

    // decoder
    dec_gather_kernel<<<(LROWS / 32 + 3) / 4, 256, 0, stream>>>(
        P16_drug, P16_dis, ell, ell + LROWS, dec_W2, dec_b2, out, LROWS);
}

// Round 17
// 252.915 us; speedup vs baseline: 1.2527x; 1.0205x over previous
//
#include <hip/hip_runtime.h>
#include <hip/hip_fp16.h>

#define D 128
#define NDRUG 20000
#define NDIS 20000
#define EDGES 640000
#define LROWS 200000
#define ROWP 264   // LDS row pitch in halves: 256 data + 8 pad (528B, 16B-aligned)

typedef unsigned short u16;
typedef __attribute__((ext_vector_type(8))) _Float16 h8v;
typedef __attribute__((ext_vector_type(4))) _Float16 h4v;
typedef __attribute__((ext_vector_type(4))) float f4v;

// ---------------- helpers ----------------

__device__ inline void h8_load(uint4 u, float f[8]) {
    float2 a = __half22float2(*(const __half2*)&u.x);
    float2 b = __half22float2(*(const __half2*)&u.y);
    float2 c = __half22float2(*(const __half2*)&u.z);
    float2 d = __half22float2(*(const __half2*)&u.w);
    f[0] = a.x; f[1] = a.y; f[2] = b.x; f[3] = b.y;
    f[4] = c.x; f[5] = c.y; f[6] = d.x; f[7] = d.y;
}

// ---------------- CSR build (r13-proven: rank2 + scan2 + sliced scatter) ----------------

__global__ __launch_bounds__(256) void rank2_kernel(
    const int* __restrict__ dA, int* __restrict__ cA, int* __restrict__ rA,
    const int* __restrict__ dB, int* __restrict__ cB, int* __restrict__ rB, int n)
{
    int i = blockIdx.x * blockDim.x + threadIdx.x;
    if (i < n) rA[i] = atomicAdd(&cA[dA[i]], 1);
    else if (i - n < n) rB[i - n] = atomicAdd(&cB[dB[i - n]], 1);
}

__global__ __launch_bounds__(1024) void scan2_kernel(int* __restrict__ c0, int* __restrict__ o0,
                                                     int* __restrict__ c1, int* __restrict__ o1,
                                                     int n) {
    int* cnt_io = (blockIdx.x == 0) ? c0 : c1;
    int* off    = (blockIdx.x == 0) ? o0 : o1;
    __shared__ int wsum[16];
    __shared__ int carry_s;
    const int tid = threadIdx.x;
    const int lane = tid & 63;
    const int wid = tid >> 6;
    if (tid == 0) { carry_s = 0; off[0] = 0; }
    __syncthreads();
    for (int start = 0; start < n; start += 1024) {
        int i = start + tid;
        int v = (i < n) ? cnt_io[i] : 0;
        int carry = carry_s;
        int s = v;
        #pragma unroll
        for (int o = 1; o < 64; o <<= 1) {
            int t = __shfl_up(s, o, 64);
            if (lane >= o) s += t;
        }
        if (lane == 63) wsum[wid] = s;
        __syncthreads();
        if (wid == 0) {
            int ws = (lane < 16) ? wsum[lane] : 0;
            #pragma unroll
            for (int o = 1; o < 16; o <<= 1) {
                int t = __shfl_up(ws, o, 64);
                if (lane >= o) ws += t;
            }
            if (lane < 16) wsum[lane] = ws;
        }
        __syncthreads();
        int woff = (wid > 0) ? wsum[wid - 1] : 0;
        int incl = s + woff + carry;
        if (i < n) {
            off[i + 1] = incl;
            cnt_io[i] = incl - v;
        }
        __syncthreads();
        if (tid == 1023) carry_s = incl;
        __syncthreads();
    }
}

#define SB 104

__global__ __launch_bounds__(256) void scatter_sliced_kernel(
    const int* __restrict__ srcA, const int* __restrict__ dstA,
    const int* __restrict__ rkA, const int* __restrict__ offA, u16* __restrict__ csrA,
    const int* __restrict__ srcB, const int* __restrict__ dstB,
    const int* __restrict__ rkB, const int* __restrict__ offB, u16* __restrict__ csrB,
    int n)
{
    int b = blockIdx.x;
    int dirB = (b >= 8 * SB);
    int bb = b - (dirB ? 8 * SB : 0);
    int s = bb & 7;
    int sub = bb >> 3;
    const int* src = dirB ? srcB : srcA;
    const int* dst = dirB ? dstB : dstA;
    const int* rk  = dirB ? rkB : rkA;
    const int* off = dirB ? offB : offA;
    u16* csr = dirB ? csrB : csrA;

    const int lo = s * 2500, hi = lo + 2500;
    const int chunk = (n + SB - 1) / SB;
    int i0 = sub * chunk;
    int i1 = i0 + chunk; i1 = i1 < n ? i1 : n;
    for (int i = i0 + threadIdx.x; i < i1; i += 256) {
        int d = dst[i];
        if (d >= lo && d < hi) {
            int pos = off[d] + rk[i];
            csr[pos] = (u16)src[i];
        }
    }
}

// ---------------- fp32 -> fp16 conversions ----------------

__global__ __launch_bounds__(256) void cvt16x2_kernel(
    const float* __restrict__ ina, __half* __restrict__ outa, int n4a,
    const float* __restrict__ inb, __half* __restrict__ outb, int n4b)
{
    int i = blockIdx.x * blockDim.x + threadIdx.x;
    const float* in; __half* out; int idx;
    if (i < n4a) { in = ina; out = outa; idx = i; }
    else if (i - n4a < n4b) { in = inb; out = outb; idx = i - n4a; }
    else return;
    float4 v = ((const float4*)in)[idx];
    __half2 a = __floats2half2_rn(v.x, v.y);
    __half2 b = __floats2half2_rn(v.z, v.w);
    uint2 u;
    u.x = *(unsigned*)&a;
    u.y = *(unsigned*)&b;
    ((uint2*)out)[idx] = u;
}

// Transposed, stacked fp16 weights for MFMA B-operands (r13-proven).
__global__ __launch_bounds__(256) void cvtwt_kernel(
    const float* __restrict__ W1l_d2s, const float* __restrict__ W1r_d2s,
    const float* __restrict__ W1l_s2d, const float* __restrict__ W1r_s2d,
    const float* __restrict__ W2l_d2s, const float* __restrict__ W2r_d2s,
    const float* __restrict__ W2l_s2d, const float* __restrict__ W2r_s2d,
    const float* __restrict__ decW1, __half* __restrict__ out)
{
    int gid = blockIdx.x * 256 + threadIdx.x;
    float v;
    if (gid < 4 * 32768) {
        int chunk = gid >> 15;
        int r = gid & 32767;
        int col = r >> 8;
        int k = r & 255;
        const float *Wl, *Wr;
        switch (chunk) {
            case 0: Wl = W1l_d2s; Wr = W1r_d2s; break;
            case 1: Wl = W1l_s2d; Wr = W1r_s2d; break;
            case 2: Wl = W2l_d2s; Wr = W2r_d2s; break;
            default: Wl = W2l_s2d; Wr = W2r_s2d; break;
        }
        const float* src = (k < 128) ? Wl : Wr;
        v = src[(size_t)(k & 127) * D + col];
    } else {
        int r = gid - 4 * 32768;
        int chunk = r >> 14;            // 0 = hi (rows 128-255), 1 = lo
        int q = r & 16383;
        int col = q >> 7;
        int k = q & 127;
        int row = k + (chunk == 0 ? 128 : 0);
        v = decW1[(size_t)row * D + col];
    }
    out[gid] = __float2half_rn(v);
}

// ---------------- SAGE gather ----------------
// r8-proven loop shape (readlane broadcast, half-wave split, pk_f16 accum);
// r17: 8 pairs in flight (2x the outstanding loads) — same shape, wider
// unroll. DO NOT add predication/dynamic shuffles (r5/r7 blowups).

__device__ inline void sage_gather(
    const __half* __restrict__ xsrc, const __half* __restrict__ xdst,
    const int* __restrict__ off, const u16* __restrict__ csr,
    __half sm[16][ROWP], int node0, int row0, int lane)
{
    const bool hiHalf = lane >= 32;
    const int lq = lane & 31;
    const int c0 = lq * 4;          // 4 halves (8B) per lane
    for (int r = 0; r < 4; ++r) {
        int node = node0 + r;
        int e0 = off[node], e1 = off[node + 1];
        int deg = e1 - e0;
        h4v acc = {(_Float16)0, (_Float16)0, (_Float16)0, (_Float16)0};
        for (int base = e0; base < e1; base += 64) {
            int nv = e1 - base; nv = nv < 64 ? nv : 64;
            int myidx = 0;
            if (lane < nv) myidx = csr[base + lane];
            int npair = nv >> 1;
            int t = 0;
            for (; t + 8 <= npair; t += 8) {
                int pa0 = __builtin_amdgcn_readlane(myidx, 2 * t + 0);
                int pb0 = __builtin_amdgcn_readlane(myidx, 2 * t + 1);
                int pa1 = __builtin_amdgcn_readlane(myidx, 2 * t + 2);
                int pb1 = __builtin_amdgcn_readlane(myidx, 2 * t + 3);
                int pa2 = __builtin_amdgcn_readlane(myidx, 2 * t + 4);
                int pb2 = __builtin_amdgcn_readlane(myidx, 2 * t + 5);
                int pa3 = __builtin_amdgcn_readlane(myidx, 2 * t + 6);
                int pb3 = __builtin_amdgcn_readlane(myidx, 2 * t + 7);
                int pa4 = __builtin_amdgcn_readlane(myidx, 2 * t + 8);
                int pb4 = __builtin_amdgcn_readlane(myidx, 2 * t + 9);
                int pa5 = __builtin_amdgcn_readlane(myidx, 2 * t + 10);
                int pb5 = __builtin_amdgcn_readlane(myidx, 2 * t + 11);
                int pa6 = __builtin_amdgcn_readlane(myidx, 2 * t + 12);
                int pb6 = __builtin_amdgcn_readlane(myidx, 2 * t + 13);
                int pa7 = __builtin_amdgcn_readlane(myidx, 2 * t + 14);
                int pb7 = __builtin_amdgcn_readlane(myidx, 2 * t + 15);
                int s0 = hiHalf ? pb0 : pa0;
                int s1 = hiHalf ? pb1 : pa1;
                int s2 = hiHalf ? pb2 : pa2;
                int s3 = hiHalf ? pb3 : pa3;
                int s4 = hiHalf ? pb4 : pa4;
                int s5 = hiHalf ? pb5 : pa5;
                int s6 = hiHalf ? pb6 : pa6;
                int s7 = hiHalf ? pb7 : pa7;
                h4v v0 = *(const h4v*)(xsrc + (size_t)s0 * D + c0);
                h4v v1 = *(const h4v*)(xsrc + (size_t)s1 * D + c0);
                h4v v2 = *(const h4v*)(xsrc + (size_t)s2 * D + c0);
                h4v v3 = *(const h4v*)(xsrc + (size_t)s3 * D + c0);
                h4v v4 = *(const h4v*)(xsrc + (size_t)s4 * D + c0);
                h4v v5 = *(const h4v*)(xsrc + (size_t)s5 * D + c0);
                h4v v6 = *(const h4v*)(xsrc + (size_t)s6 * D + c0);
                h4v v7 = *(const h4v*)(xsrc + (size_t)s7 * D + c0);
                acc += v0; acc += v1; acc += v2; acc += v3;
                acc += v4; acc += v5; acc += v6; acc += v7;
            }
            for (; t + 4 <= npair; t += 4) {
                int pa0 = __builtin_amdgcn_readlane(myidx, 2 * t + 0);
                int pb0 = __builtin_amdgcn_readlane(myidx, 2 * t + 1);
                int pa1 = __builtin_amdgcn_readlane(myidx, 2 * t + 2);
                int pb1 = __builtin_amdgcn_readlane(myidx, 2 * t + 3);
                int pa2 = __builtin_amdgcn_readlane(myidx, 2 * t + 4);
                int pb2 = __builtin_amdgcn_readlane(myidx, 2 * t + 5);
                int pa3 = __builtin_amdgcn_readlane(myidx, 2 * t + 6);
                int pb3 = __builtin_amdgcn_readlane(myidx, 2 * t + 7);
                int s0 = hiHalf ? pb0 : pa0;
                int s1 = hiHalf ? pb1 : pa1;
                int s2 = hiHalf ? pb2 : pa2;
                int s3 = hiHalf ? pb3 : pa3;
                h4v v0 = *(const h4v*)(xsrc + (size_t)s0 * D + c0);
                h4v v1 = *(const h4v*)(xsrc + (size_t)s1 * D + c0);
                h4v v2 = *(const h4v*)(xsrc + (size_t)s2 * D + c0);
                h4v v3 = *(const h4v*)(xsrc + (size_t)s3 * D + c0);
                acc += v0; acc += v1; acc += v2; acc += v3;
            }
            for (; t < npair; ++t) {
                int pa = __builtin_amdgcn_readlane(myidx, 2 * t + 0);
                int pb = __builtin_amdgcn_readlane(myidx, 2 * t + 1);
                int s = hiHalf ? pb : pa;
                h4v v = *(const h4v*)(xsrc + (size_t)s * D + c0);
                acc += v;
            }
            if (nv & 1) {
                int s = __builtin_amdgcn_readlane(myidx, nv - 1);
                if (!hiHalf) {
                    h4v v = *(const h4v*)(xsrc + (size_t)s * D + c0);
                    acc += v;
                }
            }
        }
        // combine half-waves: 2 packed shuffles + packed add
        uint2 pk = *(uint2*)&acc;
        uint2 other;
        other.x = __shfl_xor((int)pk.x, 32, 64);
        other.y = __shfl_xor((int)pk.y, 32, 64);
        acc += *(h4v*)&other;
        float inv = 1.0f / (float)(deg < 1 ? 1 : deg);
        if (!hiHalf) {
            __half2 h01 = __floats2half2_rn((float)acc[0] * inv, (float)acc[1] * inv);
            __half2 h23 = __floats2half2_rn((float)acc[2] * inv, (float)acc[3] * inv);
            uint2 w; w.x = *(unsigned*)&h01; w.y = *(unsigned*)&h23;
            *(uint2*)&sm[row0 + r][c0] = w;
        } else {
            uint2 u = *(const uint2*)(xdst + (size_t)node * D + c0);
            *(uint2*)&sm[row0 + r][128 + c0] = u;
        }
    }
}

// ---------------- fused SAGE layer kernels (gather + MFMA mm) ----------------
// Block = 16 nodes, 4 waves. dir->XCD pinning: blockIdx%8 in 0..3 -> bank A,
// 4..7 -> bank B. MFMA mapping (r2-verified). launch_bounds(256,8):
// target <=64 VGPR so 8 blocks/CU stay resident (latency-bound gather).

__global__ __launch_bounds__(256, 8) void sage_l1_kernel(
    const __half* __restrict__ xsA, const __half* __restrict__ xdA,
    const int* __restrict__ offA, const u16* __restrict__ csrA,
    const __half* __restrict__ wTA, const float* __restrict__ bA, __half* __restrict__ outA,
    const __half* __restrict__ xsB, const __half* __restrict__ xdB,
    const int* __restrict__ offB, const u16* __restrict__ csrB,
    const __half* __restrict__ wTB, const float* __restrict__ bB, __half* __restrict__ outB)
{
    __shared__ __align__(16) __half sm[16][ROWP];
    const int s8 = blockIdx.x & 7;
    const int bank = s8 >> 2;
    const int blk = ((int)blockIdx.x >> 3) * 4 + (s8 & 3);
    if (blk >= NDIS / 16) return;
    const __half* xsrc = bank ? xsB : xsA;
    const __half* xdst = bank ? xdB : xdA;
    const int* off = bank ? offB : offA;
    const u16* csr = bank ? csrB : csrA;
    const __half* wT = bank ? wTB : wTA;
    const float* bias = bank ? bB : bA;
    __half* out16 = bank ? outB : outA;

    const int lane = threadIdx.x & 63;
    const int wid = threadIdx.x >> 6;
    const int node0 = blk * 16;

    sage_gather(xsrc, xdst, off, csr, sm, node0 + wid * 4, wid * 4, lane);
    __syncthreads();

    const int lr = lane & 15;
    const int g = lane >> 4;
    const int colbase = wid * 32;
    f4v acc0 = {0.f, 0.f, 0.f, 0.f};
    f4v acc1 = {0.f, 0.f, 0.f, 0.f};
    #pragma unroll
    for (int t = 0; t < 8; ++t) {
        h8v a = *(const h8v*)&sm[lr][t * 32 + g * 8];
        h8v b0 = *(const h8v*)(wT + (size_t)(colbase + lr) * 256 + t * 32 + g * 8);
        h8v b1 = *(const h8v*)(wT + (size_t)(colbase + 16 + lr) * 256 + t * 32 + g * 8);
        acc0 = __builtin_amdgcn_mfma_f32_16x16x32_f16(a, b0, acc0, 0, 0, 0);
        acc1 = __builtin_amdgcn_mfma_f32_16x16x32_f16(a, b1, acc1, 0, 0, 0);
    }
    #pragma unroll
    for (int reg = 0; reg < 4; ++reg) {
        int row = g * 4 + reg;
        int col0 = colbase + lr;
        int col1 = colbase + 16 + lr;
        float v0 = fmaxf(acc0[reg] + bias[col0], 0.f);
        float v1 = fmaxf(acc1[reg] + bias[col1], 0.f);
        out16[(size_t)(node0 + row) * D + col0] = __float2half_rn(v0);
        out16[(size_t)(node0 + row) * D + col1] = __float2half_rn(v1);
    }
}

__global__ __launch_bounds__(256, 8) void sage_l2_kernel(
    const __half* __restrict__ xsA, const __half* __restrict__ xdA,
    const int* __restrict__ offA, const u16* __restrict__ csrA,
    const __half* __restrict__ wTA, const float* __restrict__ bA,
    const __half* __restrict__ wdTA, const float* __restrict__ pbA, __half* __restrict__ PoutA,
    const __half* __restrict__ xsB, const __half* __restrict__ xdB,
    const int* __restrict__ offB, const u16* __restrict__ csrB,
    const __half* __restrict__ wTB, const float* __restrict__ bB,
    const __half* __restrict__ wdTB, const float* __restrict__ pbB, __half* __restrict__ PoutB)
{
    __shared__ __align__(16) __half sm[16][ROWP];
    const int s8 = blockIdx.x & 7;
    const int bank = s8 >> 2;
    const int blk = ((int)blockIdx.x >> 3) * 4 + (s8 & 3);
    if (blk >= NDIS / 16) return;
    const __half* xsrc = bank ? xsB : xsA;
    const __half* xdst = bank ? xdB : xdA;
    const int* off = bank ? offB : offA;
    const u16* csr = bank ? csrB : csrA;
    const __half* wT = bank ? wTB : wTA;
    const float* bias = bank ? bB : bA;
    const __half* wdT = bank ? wdTB : wdTA;
    const float* pb = bank ? pbB : pbA;
    __half* Pout = bank ? PoutB : PoutA;

    const int lane = threadIdx.x & 63;
    const int wid = threadIdx.x >> 6;
    const int node0 = blk * 16;

    sage_gather(xsrc, xdst, off, csr, sm, node0 + wid * 4, wid * 4, lane);
    __syncthreads();

    const int lr = lane & 15;
    const int g = lane >> 4;
    const int colbase = wid * 32;
    f4v acc0 = {0.f, 0.f, 0.f, 0.f};
    f4v acc1 = {0.f, 0.f, 0.f, 0.f};
    #pragma unroll
    for (int t = 0; t < 8; ++t) {
        h8v a = *(const h8v*)&sm[lr][t * 32 + g * 8];
        h8v b0 = *(const h8v*)(wT + (size_t)(colbase + lr) * 256 + t * 32 + g * 8);
        h8v b1 = *(const h8v*)(wT + (size_t)(colbase + 16 + lr) * 256 + t * 32 + g * 8);
        acc0 = __builtin_amdgcn_mfma_f32_16x16x32_f16(a, b0, acc0, 0, 0, 0);
        acc1 = __builtin_amdgcn_mfma_f32_16x16x32_f16(a, b1, acc1, 0, 0, 0);
    }

    __syncthreads();
    #pragma unroll
    for (int reg = 0; reg < 4; ++reg) {
        int row = g * 4 + reg;
        sm[row][colbase + lr] = __float2half_rn(acc0[reg] + bias[colbase + lr]);
        sm[row][colbase + 16 + lr] = __float2half_rn(acc1[reg] + bias[colbase + 16 + lr]);
    }
    __syncthreads();

    f4v p0 = {0.f, 0.f, 0.f, 0.f};
    f4v p1 = {0.f, 0.f, 0.f, 0.f};
    #pragma unroll
    for (int t = 0; t < 4; ++t) {
        h8v a = *(const h8v*)&sm[lr][t * 32 + g * 8];
        h8v b0 = *(const h8v*)(wdT + (size_t)(colbase + lr) * 128 + t * 32 + g * 8);
        h8v b1 = *(const h8v*)(wdT + (size_t)(colbase + 16 + lr) * 128 + t * 32 + g * 8);
        p0 = __builtin_amdgcn_mfma_f32_16x16x32_f16(a, b0, p0, 0, 0, 0);
        p1 = __builtin_amdgcn_mfma_f32_16x16x32_f16(a, b1, p1, 0, 0, 0);
    }
    #pragma unroll
    for (int reg = 0; reg < 4; ++reg) {
        int row = g * 4 + reg;
        int col0 = colbase + lr;
        int col1 = colbase + 16 + lr;
        float v0 = p0[reg] + (pb ? pb[col0] : 0.f);
        float v1 = p1[reg] + (pb ? pb[col1] : 0.f);
        Pout[(size_t)(node0 + row) * D + col0] = __float2half_rn(v0);
        Pout[(size_t)(node0 + row) * D + col1] = __float2half_rn(v1);
    }
}

// ---------------- decoder (r8-proven) ----------------

__global__ __launch_bounds__(256) void dec_gather_kernel(
    const __half* __restrict__ Pd, const __half* __restrict__ Ps,
    const int* __restrict__ row_idx, const int* __restrict__ col_idx,
    const float* __restrict__ W2, const float* __restrict__ b2,
    float* __restrict__ out, int nrows)
{
    const int lane = threadIdx.x & 63;
    const int wid = threadIdx.x >> 6;
    const int g = lane >> 4;
    const int lq = lane & 15;
    const int wave_id = blockIdx.x * 4 + wid;
    const int e0 = wave_id * 32;
    if (e0 >= nrows) return;

    const int c0 = lq * 8;
    float w2v[8];
    #pragma unroll
    for (int i = 0; i < 8; ++i) w2v[i] = W2[c0 + i];
    float b2v = b2[0];

    #pragma unroll 2
    for (int it = 0; it < 8; ++it) {
        int ei = it * 4 + g;
        int rr = e0 + ei;
        int ri = row_idx[rr];
        int ci = col_idx[rr];
        uint4 ua = *(const uint4*)(Pd + (size_t)ri * D + c0);
        uint4 ub = *(const uint4*)(Ps + (size_t)ci * D + c0);
        float fa[8], fb[8];
        h8_load(ua, fa);
        h8_load(ub, fb);
        float v = 0.f;
        #pragma unroll
        for (int i = 0; i < 8; ++i)
            v = fmaf(fmaxf(fa[i] + fb[i], 0.f), w2v[i], v);
        v += __shfl_xor(v, 1, 64);
        v += __shfl_xor(v, 2, 64);
        v += __shfl_xor(v, 4, 64);
        v += __shfl_xor(v, 8, 64);
        if (lq == 0) out[rr] = v + b2v;
    }
}

// ---------------- launcher ----------------

extern "C" void kernel_launch(void* const* d_in, const int* in_sizes, int n_in,
                              void* d_out, int out_size, void* d_ws, size_t ws_size,
                              hipStream_t stream) {
    const float* x_drug = (const float*)d_in[0];
    const float* x_dis  = (const float*)d_in[1];
    const int* ei_d2s = (const int*)d_in[2];
    const int* ei_s2d = (const int*)d_in[3];
    const int* ell    = (const int*)d_in[4];
    const float* W1l_d2s = (const float*)d_in[5];
    const float* W1r_d2s = (const float*)d_in[6];
    const float* W1l_s2d = (const float*)d_in[7];
    const float* W1r_s2d = (const float*)d_in[8];
    const float* W2l_d2s = (const float*)d_in[9];
    const float* W2r_d2s = (const float*)d_in[10];
    const float* W2l_s2d = (const float*)d_in[11];
    const float* W2r_s2d = (const float*)d_in[12];
    const float* b1_d2s = (const float*)d_in[13];
    const float* b1_s2d = (const float*)d_in[14];
    const float* b2_d2s = (const float*)d_in[15];
    const float* b2_s2d = (const float*)d_in[16];
    const float* dec_W1 = (const float*)d_in[17];
    const float* dec_b1 = (const float*)d_in[18];
    const float* dec_W2 = (const float*)d_in[19];
    const float* dec_b2 = (const float*)d_in[20];
    float* out = (float*)d_out;

    char* ws = (char*)d_ws;
    size_t o = 0;
    auto take = [&](size_t bytes) -> char* {
        char* p = ws + o;
        o += (bytes + 255) & ~(size_t)255;
        return p;
    };
    int* off_d2s = (int*)take((NDIS + 1) * sizeof(int));
    int* cnt_d2s = (int*)take(NDIS * sizeof(int));
    u16* csr_d2s = (u16*)take((size_t)EDGES * sizeof(u16));
    int* rk_d2s  = (int*)take((size_t)EDGES * sizeof(int));
    int* off_s2d = (int*)take((NDRUG + 1) * sizeof(int));
    int* cnt_s2d = (int*)take(NDRUG * sizeof(int));
    u16* csr_s2d = (u16*)take((size_t)EDGES * sizeof(u16));
    int* rk_s2d  = (int*)take((size_t)EDGES * sizeof(int));
    __half* x16_drug = (__half*)take((size_t)NDRUG * D * sizeof(__half));
    __half* x16_dis  = (__half*)take((size_t)NDIS * D * sizeof(__half));
    __half* h16_dis  = (__half*)take((size_t)NDIS * D * sizeof(__half));
    __half* h16_drug = (__half*)take((size_t)NDRUG * D * sizeof(__half));
    __half* P16_drug = (__half*)take((size_t)NDRUG * D * sizeof(__half));
    __half* P16_dis  = (__half*)take((size_t)NDIS * D * sizeof(__half));
    __half* w16 = (__half*)take((size_t)163840 * sizeof(__half));

    __half* wT_l1_d2s = w16 + 0 * 32768;
    __half* wT_l1_s2d = w16 + 1 * 32768;
    __half* wT_l2_d2s = w16 + 2 * 32768;
    __half* wT_l2_s2d = w16 + 3 * 32768;
    __half* wdT_hi    = w16 + 4 * 32768;            // dec_W1 rows 128-255 (bank A)
    __half* wdT_lo    = w16 + 4 * 32768 + 16384;    // dec_W1 rows 0-127  (bank B)

    hipMemsetAsync(cnt_d2s, 0, NDIS * sizeof(int), stream);
    hipMemsetAsync(cnt_s2d, 0, NDRUG * sizeof(int), stream);

    cvtwt_kernel<<<640, 256, 0, stream>>>(
        W1l_d2s, W1r_d2s, W1l_s2d, W1r_s2d,
        W2l_d2s, W2r_d2s, W2l_s2d, W2r_s2d, dec_W1, w16);

    cvt16x2_kernel<<<(2 * NDRUG * D / 4 + 255) / 256, 256, 0, stream>>>(
        x_drug, x16_drug, NDRUG * D / 4, x_dis, x16_dis, NDIS * D / 4);

    // CSR build (r13-proven): rank2 -> scan2 -> sliced scatter
    const int EB2 = (2 * EDGES + 255) / 256;
    rank2_kernel<<<EB2, 256, 0, stream>>>(ei_d2s + EDGES, cnt_d2s, rk_d2s,
                                          ei_s2d + EDGES, cnt_s2d, rk_s2d, EDGES);
    scan2_kernel<<<2, 1024, 0, stream>>>(cnt_d2s, off_d2s, cnt_s2d, off_s2d, NDIS);
    scatter_sliced_kernel<<<2 * 8 * SB, 256, 0, stream>>>(
        ei_d2s, ei_d2s + EDGES, rk_d2s, off_d2s, csr_d2s,
        ei_s2d, ei_s2d + EDGES, rk_s2d, off_s2d, csr_s2d, EDGES);

    // sage grids: 1250 blocks/bank, 8-padded for the %8 dir->XCD pinning
    const int SGRID = ((2 * (NDIS / 16) + 7) / 8) * 8 + 8;   // 2504

    // layer 1: bank A = d2s -> h_dis, bank B = s2d -> h_drug
    sage_l1_kernel<<<SGRID, 256, 0, stream>>>(
        x16_drug, x16_dis, off_d2s, csr_d2s, wT_l1_d2s, b1_d2s, h16_dis,
        x16_dis, x16_drug, off_s2d, csr_s2d, wT_l1_s2d, b1_s2d, h16_drug);

    // layer 2 + fused decoder projection:
    //   P_dis = z_dis @ dec_W1[128:256] + dec_b1 ; P_drug = z_drug @ dec_W1[0:128]
    sage_l2_kernel<<<SGRID, 256, 0, stream>>>(
        h16_drug, h16_dis, off_d2s, csr_d2s, wT_l2_d2s, b2_d2s, wdT_hi, dec_b1, P16_dis,
        h16_dis, h16_drug, off_s2d, csr_s2d, wT_l2_s2d, b2_s2d, wdT_lo, nullptr, P16_drug);

    // decoder
    dec_gather_kernel<<<(LROWS / 32 + 3) / 4, 256, 0, stream>>>(
        P16_drug, P16_dis, ell, ell + LROWS, dec_W2, dec_b2, out, LROWS);
}